// Round 12
// baseline (296.017 us; speedup 1.0000x reference)
//
#include <hip/hip_runtime.h>
#include <math.h>

// Problem constants (fixed shapes)
#define N_PTS 32768
#define C_DIM 128
#define K_NB  16
#define G_DIM 8

// Workspace float offsets
#define OF_PW     0          // 128*8  P @ Ww1 (fp32)
#define OF_STATQ  1024       // 256 (sum, sumsq) of q_lin
#define OF_STATK  1280       // 256
#define OF_STATG1 1536       // 256
#define OF_STATH  1792       // 16
#define OF_UMAXP  1808       // 4*128 encoded max(q_lin raw) per seg
#define OF_UMAXN  2320       // 4*128 encoded max(-q_lin raw) per seg (zero region = 1024..2832)
#define OF_GSG    2832       // 4*128 precomputed gate-seg vector (gprep)
// bf16 [n][k] operands, 16384 shorts = 8192 floats each
#define OF_WQT    4096
#define OF_WKT    12288
#define OF_WVT    20480
#define OF_WG1T   28672
#define OF_PTMIT  36864
#define OF_QW     65536      // N*8
#define OF_KW     327680     // N*8
#define OF_GATE   589824     // N*8 (unused since round 12 — gate lives in LDS)
#define OF_G1     1048576    // N*128
#define OF_V      5242880    // N*128

typedef short bf16x8 __attribute__((ext_vector_type(8)));
typedef float f32x4  __attribute__((ext_vector_type(4)));

#define LSTR 136   // bf16 LDS row stride (272 B) — cayley tiles

__device__ __forceinline__ unsigned f2bf(float f) {
  unsigned u = __float_as_uint(f);
  return (u + 0x7fffu + ((u >> 16) & 1u)) >> 16;
}
__device__ __forceinline__ float bf2f(short s) {
  return __uint_as_float(((unsigned)(unsigned short)s) << 16);
}
__device__ __forceinline__ unsigned fenc(float f) {
  unsigned b = __float_as_uint(f);
  return (b & 0x80000000u) ? ~b : (b | 0x80000000u);
}
__device__ __forceinline__ float fdec(unsigned u) {
  unsigned b = (u & 0x80000000u) ? (u & 0x7fffffffu) : ~u;
  return __uint_as_float(b);
}
__device__ __forceinline__ bf16x8 pack_bf8(float4 a, float4 b) {
  bf16x8 r;
  r[0] = (short)f2bf(a.x); r[1] = (short)f2bf(a.y);
  r[2] = (short)f2bf(a.z); r[3] = (short)f2bf(a.w);
  r[4] = (short)f2bf(b.x); r[5] = (short)f2bf(b.y);
  r[6] = (short)f2bf(b.z); r[7] = (short)f2bf(b.w);
  return r;
}

// async 16B global -> LDS (no VGPR round-trip, drained by __syncthreads)
__device__ __forceinline__ void g2l16(const void* g, void* l) {
  __builtin_amdgcn_global_load_lds(
      (const __attribute__((address_space(1))) void*)g,
      (__attribute__((address_space(3))) void*)l, 16, 0, 0);
}

// Async-stage a [128][128] bf16 tile (32 KB) into LINEAR LDS.
// global_load_lds writes lds[base + lane*16]; we pre-swizzle the per-lane
// GLOBAL source with the involution  byte ^ ((row&7)<<4)  so the swizzled
// ds_reads in mfma1 are bank-balanced. Validated rounds 3-11.
__device__ __forceinline__ void stage_async(short* dst, const short* __restrict__ src, int tid) {
  int lane = tid & 63, wv = tid >> 6;
  #pragma unroll
  for (int it = 0; it < 8; ++it) {
    int chunk = it*256 + wv*64;            // wave-uniform 16B-chunk base
    int D = (chunk + lane)*16;             // this lane's linear LDS byte offset
    int gs = D ^ (((D >> 8) & 7) << 4);    // inverse (== forward) swizzle
    g2l16((const char*)src + gs, (char*)dst + chunk*16);
  }
}

// One 16x16x32 MFMA column-tile over swizzle-staged LDS B: returns af @ B
// for output col group; caller passes row = nt*16 + l15.
__device__ __forceinline__ f32x4 mfma1(const short* Bb, const bf16x8* a4, int row, int quad) {
  f32x4 ac = {0.f, 0.f, 0.f, 0.f};
  int sx = (row & 7) << 4;
  #pragma unroll
  for (int ks = 0; ks < 4; ++ks) {
    const char* p = (const char*)Bb + (((row*256) + ks*64 + quad*16) ^ sx);
    ac = __builtin_amdgcn_mfma_f32_16x16x32_bf16(a4[ks], *(const bf16x8*)p, ac, 0, 0, 0);
  }
  return ac;
}

// ---------------------------------------------------------------------------
// cayley: unchanged from round 8 (coalesced staging, validated; outputs
// bitwise identical).
__global__ __launch_bounds__(256) void cayley(const float* __restrict__ Sp,
    const float* __restrict__ Ww1,
    const float* __restrict__ Wq, const float* __restrict__ Wk,
    const float* __restrict__ Wv, const float* __restrict__ Wg1,
    short* __restrict__ WqT, short* __restrict__ WkT,
    short* __restrict__ WvT, short* __restrict__ Wg1T,
    short* __restrict__ PTmIT, float* __restrict__ PW,
    float* __restrict__ statz)
{
  __shared__ __align__(16) short Ssh[128*LSTR];
  __shared__ float x0[128], x1[128];
  int bx = blockIdx.x, tid = threadIdx.x;
  if (bx >= 64) {
    if (bx < 80) {
      int idx = bx - 64, widx = idx >> 2, qr = idx & 3;
      const float* src = (widx == 0) ? Wq : (widx == 1) ? Wk : (widx == 2) ? Wv : Wg1;
      short* dst = (widx == 0) ? WqT : (widx == 1) ? WkT : (widx == 2) ? WvT : Wg1T;
      const float4* s4 = (const float4*)src;
      short* T = Ssh;                    // [128][40] shorts: 80B rows, 16B-aligned
      #pragma unroll
      for (int it = 0; it < 4; ++it) {
        int q = it*256 + tid; int kloc = q >> 5, n4 = q & 31;
        float4 v = s4[(qr*32 + kloc)*32 + n4];
        T[(n4*4+0)*40 + kloc] = (short)f2bf(v.x);
        T[(n4*4+1)*40 + kloc] = (short)f2bf(v.y);
        T[(n4*4+2)*40 + kloc] = (short)f2bf(v.z);
        T[(n4*4+3)*40 + kloc] = (short)f2bf(v.w);
      }
      __syncthreads();
      #pragma unroll
      for (int it = 0; it < 2; ++it) {
        int i2 = it*256 + tid;           // 512 chunks of 8 shorts (128 rows x 4)
        int n = i2 >> 2, part = i2 & 3;
        uint4 val = *(const uint4*)&T[n*40 + part*8];
        *(uint4*)&dst[n*128 + qr*32 + part*8] = val;
      }
    } else {
      #pragma unroll
      for (int it = 0; it < 8; ++it) {
        int idx = it*256 + tid;
        if (idx < 1808) statz[idx] = 0.f;
      }
    }
    return;
  }
  int c0 = bx*2, c1 = c0 + 1;
  // stage antisymmetrized S: coalesced row reads; mirror for lower triangle
  {
    const float4* s4 = (const float4*)Sp;
    #pragma unroll
    for (int it = 0; it < 16; ++it) {
      int idx = it*256 + tid;            // 4096 float4 chunks, row-major
      int i = idx >> 5, j0 = (idx & 31) * 4;
      float4 v = s4[idx];
      #pragma unroll
      for (int u = 0; u < 4; ++u) {
        int j = j0 + u;
        float val = (&v.x)[u];
        if (j > i) {
          unsigned b = f2bf(val);
          Ssh[i*LSTR + j] = (short)b;                    // upper:  bf16(v)
          Ssh[j*LSTR + i] = (short)(b ^ 0x8000u);        // lower: -bf16(v) == bf16(-v)
        } else if (j == i) {
          Ssh[i*LSTR + j] = 0;                           // diagonal
        }
      }
    }
  }
  if (tid < 128) {
    x0[tid] = (tid == c0) ? 1.f : 0.f;
    x1[tid] = (tid == c1) ? 1.f : 0.f;
  }
  __syncthreads();
  int i = tid >> 1, h = tid & 1;
  const short* srow = &Ssh[i*LSTR + h*64];
  for (int t = 0; t < 16; ++t) {
    float a0 = 0.f, a1 = 0.f;
    #pragma unroll
    for (int jq = 0; jq < 16; ++jq) {
      short4 sv = *(const short4*)&srow[jq*4];
      #pragma unroll
      for (int u = 0; u < 4; ++u) {
        float s = bf2f((&sv.x)[u]);
        int j = h*64 + jq*4 + u;
        a0 = fmaf(s, x0[j], a0);
        a1 = fmaf(s, x1[j], a1);
      }
    }
    a0 += __shfl_xor(a0, 1);
    a1 += __shfl_xor(a1, 1);
    __syncthreads();
    if (h == 0) {
      x0[i] = a0 + ((i == c0) ? 1.f : 0.f);
      x1[i] = a1 + ((i == c1) ? 1.f : 0.f);
    }
    __syncthreads();
  }
  if (tid < 128) {
    PTmIT[c0*128 + tid] = (short)f2bf(2.f*x0[tid] - ((tid == c0) ? 2.f : 0.f));
  } else {
    int t = tid - 128;
    PTmIT[c1*128 + t] = (short)f2bf(2.f*x1[t] - ((t == c1) ? 2.f : 0.f));
  }
  if (tid < 16) {
    int cc = tid >> 3, g = tid & 7;
    const float* xv = cc ? x1 : x0;
    int c = cc ? c1 : c0;
    float acc = 0.f;
    #pragma unroll 8
    for (int j = 0; j < 128; ++j) acc = fmaf(xv[j], Ww1[j*8 + g], acc);
    PW[c*8 + g] = 2.f*acc - Ww1[c*8 + g];
  }
}

// ---------------------------------------------------------------------------
// qkv: unchanged (validated): 64-row blocks x 512, A direct from feat,
// B async-staged swizzled + double-buffered, RAW minmax.
__global__ __launch_bounds__(256, 2) void qkv_mfma(const float* __restrict__ feat,
    const short* __restrict__ WqT, const short* __restrict__ WkT, const short* __restrict__ WvT,
    const float* __restrict__ bq, const float* __restrict__ bk, const float* __restrict__ bv,
    float* __restrict__ Vv,
    float* __restrict__ statq, float* __restrict__ statk,
    unsigned* __restrict__ umaxp, unsigned* __restrict__ umaxn)
{
  __shared__ __align__(16) short Bb0[128*128];   // 32768 B
  __shared__ __align__(16) short Bb1[128*128];   // 32768 B
  __shared__ float ssum[2][128], ssq[2][128];
  __shared__ unsigned ump[128], umn[128];
  int tid = threadIdx.x, row0 = blockIdx.x * 64, seg = row0 >> 13;
  int lane = tid & 63, w = tid >> 6, l15 = lane & 15, quad = lane >> 4;
  stage_async(Bb0, WqT, tid);                  // async, in flight during setup
  if (tid < 128) {
    ssum[0][tid] = 0.f; ssum[1][tid] = 0.f;
    ssq[0][tid] = 0.f;  ssq[1][tid] = 0.f;
    ump[tid] = 0u; umn[tid] = 0u;
  }
  // A-fragments: direct from feat (read once, used by all 3 GEMMs)
  bf16x8 af[4];
  {
    long rbase = (long)(row0 + w*16 + l15) * 128;
    #pragma unroll
    for (int ks = 0; ks < 4; ++ks) {
      int c0 = ks*32 + quad*8;
      float4 v0 = *(const float4*)&feat[rbase + c0];
      float4 v1 = *(const float4*)&feat[rbase + c0 + 4];
      af[ks] = pack_bf8(v0, v1);
    }
  }
  __syncthreads();                       // S0: Bb0 staged, stats init
  stage_async(Bb1, WkT, tid);            // flies during GEMM-q
  // ---- q: GEMM + stats + raw minmax
  {
    #pragma unroll
    for (int nt = 0; nt < 8; ++nt) {
      f32x4 ac = mfma1(Bb0, af, nt*16 + l15, quad);
      int col = nt*16 + l15;
      float bb = bq[col];
      float s = 0.f, s2 = 0.f, mx = -1e30f, mn = 1e30f;
      #pragma unroll
      for (int r = 0; r < 4; ++r) {
        float raw = ac[r];
        float v = raw + bb;
        s += v; s2 = fmaf(v, v, s2);
        mx = fmaxf(mx, raw); mn = fminf(mn, raw);   // raw minmax (bias folded later)
      }
      s += __shfl_xor(s, 16); s += __shfl_xor(s, 32);
      s2 += __shfl_xor(s2, 16); s2 += __shfl_xor(s2, 32);
      mx = fmaxf(mx, __shfl_xor(mx, 16)); mx = fmaxf(mx, __shfl_xor(mx, 32));
      mn = fminf(mn, __shfl_xor(mn, 16)); mn = fminf(mn, __shfl_xor(mn, 32));
      if (lane < 16) {
        atomicAdd(&ssum[0][col], s); atomicAdd(&ssq[0][col], s2);
        atomicMax(&ump[col], fenc(mx)); atomicMax(&umn[col], fenc(-mn));
      }
    }
  }
  __syncthreads();                       // S1: Bb1 staged, Bb0 reads done
  stage_async(Bb0, WvT, tid);            // flies during GEMM-k
  // ---- k: GEMM + stats
  {
    #pragma unroll
    for (int nt = 0; nt < 8; ++nt) {
      f32x4 ac = mfma1(Bb1, af, nt*16 + l15, quad);
      int col = nt*16 + l15;
      float bb = bk[col];
      float s = 0.f, s2 = 0.f;
      #pragma unroll
      for (int r = 0; r < 4; ++r) {
        float v = ac[r] + bb;
        s += v; s2 = fmaf(v, v, s2);
      }
      s += __shfl_xor(s, 16); s += __shfl_xor(s, 32);
      s2 += __shfl_xor(s2, 16); s2 += __shfl_xor(s2, 32);
      if (lane < 16) { atomicAdd(&ssum[1][col], s); atomicAdd(&ssq[1][col], s2); }
    }
  }
  __syncthreads();                       // S2: Bb0(Wv) staged, Bb1 reads done
  // ---- v: GEMM + store
  {
    #pragma unroll
    for (int nt = 0; nt < 8; ++nt) {
      f32x4 ac = mfma1(Bb0, af, nt*16 + l15, quad);
      int col = nt*16 + l15;
      float bb = bv[col];
      #pragma unroll
      for (int r = 0; r < 4; ++r)
        Vv[(long)(row0 + w*16 + quad*4 + r)*128 + col] = ac[r] + bb;
    }
  }
  __syncthreads();                       // S3: LDS stats complete
  if (tid < 128) {
    atomicAdd(&statq[tid], ssum[0][tid]); atomicAdd(&statq[128 + tid], ssq[0][tid]);
    atomicAdd(&statk[tid], ssum[1][tid]); atomicAdd(&statk[128 + tid], ssq[1][tid]);
    atomicMax(&umaxp[seg*128 + tid], ump[tid]);
    atomicMax(&umaxn[seg*128 + tid], umn[tid]);
  }
}

// ---------------------------------------------------------------------------
// gprep: hoisted per-segment gate vector (unchanged, validated round 7).
__global__ __launch_bounds__(128) void gprep(
    const float* __restrict__ statq,
    const float* __restrict__ gq, const float* __restrict__ bnq,
    const float* __restrict__ bq,
    const unsigned* __restrict__ umaxp, const unsigned* __restrict__ umaxn,
    const float* __restrict__ Wg1, const float* __restrict__ bg1,
    float* __restrict__ gsgO)
{
  __shared__ float gml[128];
  int s = blockIdx.x, tid = threadIdx.x;   // 128 threads
  const float invn = 1.f / 32768.f;
  {
    float m = statq[tid]*invn, vv = fmaf(-m, m, statq[128 + tid]*invn);
    float a = rsqrtf(vv + 1e-5f) * gq[tid];
    float b = fmaf(-m, a, bnq[tid]);
    float cb2 = fmaf(a, bq[tid], b);
    float mx = fdec(umaxp[s*128 + tid]);
    float mn = -fdec(umaxn[s*128 + tid]);
    gml[tid] = fmaxf(0.f, fmaxf(fmaf(a, mx, cb2), fmaf(a, mn, cb2)));
  }
  __syncthreads();
  float acc = bg1[tid];
  #pragma unroll 8
  for (int j = 0; j < 128; ++j)
    acc = fmaf(gml[j], Wg1[(128 + j)*128 + tid], acc);
  gsgO[s*128 + tid] = acc;
}

// ---------------------------------------------------------------------------
// rqkw: round-9 validated form (unchanged). 64-row blocks x 512, ALL 4
// waves in EVERY GEMM; single bn tile time-shared; per-wave stat scratch.
__global__ __launch_bounds__(256, 2) void rqkw(
    const float* __restrict__ feat,
    const short* __restrict__ WqT, const short* __restrict__ WkT,
    const short* __restrict__ PTmIT, const short* __restrict__ Wg1T,
    const float* __restrict__ coord,
    const float* __restrict__ bq, const float* __restrict__ bk,
    const float* __restrict__ statq, const float* __restrict__ statk,
    const float* __restrict__ gq, const float* __restrict__ bnq,
    const float* __restrict__ gk, const float* __restrict__ bnk,
    const float* __restrict__ gsgG,
    const float* __restrict__ PW, const float* __restrict__ bw1,
    float* __restrict__ qw, float* __restrict__ kw,
    float* __restrict__ g1, float* __restrict__ statg1)
{
  __shared__ __align__(16) char arena[81920];
  short* Bb0  = (short*)arena;
  short* Bb1  = (short*)(arena + 32768);
  char*  bnS  = arena + 65536;               // 16384 B (64 rows x 256 B)
  float* xsq  = (float*)arena;
  float* xsk  = (float*)(arena + 33792);
  float* pws  = (float*)(arena + 67584);
  float* ssum4 = (float*)(arena + 71680);    // [4][128]
  float* ssq4  = (float*)(arena + 73728);    // [4][128]
  int tid = threadIdx.x, row0 = blockIdx.x * 64, seg = row0 >> 13;
  int lane = tid & 63, w = tid >> 6, l15 = lane & 15, quad = lane >> 4;
  stage_async(Bb0, WqT, tid);            // both weight tiles in flight
  stage_async(Bb1, WkT, tid);            // during all setup below
  bf16x8 af[4];
  {
    long rbase = (long)(row0 + w*16 + l15) * 128;
    #pragma unroll
    for (int ks = 0; ks < 4; ++ks) {
      int c0 = ks*32 + quad*8;
      float4 v0 = *(const float4*)&feat[rbase + c0];
      float4 v1 = *(const float4*)&feat[rbase + c0 + 4];
      af[ks] = pack_bf8(v0, v1);
    }
  }
  float caRq[8], cbRq[8], caRk[8], cbRk[8];
  {
    const float invn = 1.f / 32768.f;
    #pragma unroll
    for (int nt = 0; nt < 8; ++nt) {
      int col = nt*16 + l15;
      float m = statq[col]*invn, vv = fmaf(-m, m, statq[128 + col]*invn);
      float a = rsqrtf(vv + 1e-5f) * gq[col];
      float b = fmaf(-m, a, bnq[col]);
      caRq[nt] = a; cbRq[nt] = fmaf(a, bq[col], b);
      m = statk[col]*invn; vv = fmaf(-m, m, statk[128 + col]*invn);
      a = rsqrtf(vv + 1e-5f) * gk[col];
      b = fmaf(-m, a, bnk[col]);
      caRk[nt] = a; cbRk[nt] = fmaf(a, bk[col], b);
    }
  }
  float gsR[8];
  #pragma unroll
  for (int nt = 0; nt < 8; ++nt)
    gsR[nt] = gsgG[seg*128 + nt*16 + l15];
  __syncthreads();                       // S0: Bb0(Wq)+Bb1(Wk) staged
  float bnl_q[32], bnl_k[32];
  // ---- GEMM1q (ALL waves, Bb0) + BN -> bnS tile + bnl_q regs
  {
    #pragma unroll
    for (int nt = 0; nt < 8; ++nt) {
      f32x4 ac = mfma1(Bb0, af, nt*16 + l15, quad);
      int col = nt*16 + l15;
      float A = caRq[nt], B = cbRq[nt];
      #pragma unroll
      for (int r = 0; r < 4; ++r) {
        float v = fmaxf(0.f, fmaf(A, ac[r], B));
        bnl_q[nt*4 + r] = v;
        int row = w*16 + quad*4 + r;
        int ba = (row*256 + col*2) ^ ((row & 7) << 4);
        *(short*)(bnS + ba) = (short)f2bf(v);
      }
    }
  }
  __syncthreads();                       // S1: Bb0(Wq) reads done; bnS(q) done
  stage_async(Bb0, PTmIT, tid);          // hidden under GEMM1k
  // ---- GEMM1k (ALL waves, Bb1) -> bnl_k regs only
  {
    #pragma unroll
    for (int nt = 0; nt < 8; ++nt) {
      f32x4 ac = mfma1(Bb1, af, nt*16 + l15, quad);
      float A = caRk[nt], B = cbRk[nt];
      #pragma unroll
      for (int r = 0; r < 4; ++r)
        bnl_k[nt*4 + r] = fmaxf(0.f, fmaf(A, ac[r], B));
    }
  }
  __syncthreads();                       // S2: Bb0(PTmI) ready; Bb1 reads done
  stage_async(Bb1, Wg1T, tid);           // hidden under GEMM2q
  bf16x8 af2q[4];
  {
    int rowA = w*16 + l15, sx2 = (rowA & 7) << 4;
    #pragma unroll
    for (int ks = 0; ks < 4; ++ks)
      af2q[ks] = *(const bf16x8*)(bnS + ((rowA*256 + ks*64 + quad*16) ^ sx2));
  }
  // ---- GEMM2q: rotation for q (ALL waves, Bb0 = PTmI)
  f32x4 accv_q[8];
  #pragma unroll
  for (int nt = 0; nt < 8; ++nt)
    accv_q[nt] = mfma1(Bb0, af2q, nt*16 + l15, quad);
  __syncthreads();                       // S3: af2q reads done; Bb1(Wg1) ready
  // ---- rewrite bnS with bn(k)
  {
    #pragma unroll
    for (int nt = 0; nt < 8; ++nt) {
      int col = nt*16 + l15;
      #pragma unroll
      for (int r = 0; r < 4; ++r) {
        int row = w*16 + quad*4 + r;
        int ba = (row*256 + col*2) ^ ((row & 7) << 4);
        *(short*)(bnS + ba) = (short)f2bf(bnl_k[nt*4 + r]);
      }
    }
  }
  __syncthreads();                       // S4: bnS(k) complete
  bf16x8 af2k[4];
  {
    int rowA = w*16 + l15, sx2 = (rowA & 7) << 4;
    #pragma unroll
    for (int ks = 0; ks < 4; ++ks)
      af2k[ks] = *(const bf16x8*)(bnS + ((rowA*256 + ks*64 + quad*16) ^ sx2));
  }
  // ---- GEMM2k (Bb0 = PTmI) + GEMM3 (Bb1 = Wg1, af2q) with reg-held stats
  f32x4 accv_k[8];
  float sred[8], s2red[8];
  {
    #pragma unroll
    for (int nt = 0; nt < 8; ++nt) {
      accv_k[nt] = mfma1(Bb0, af2k, nt*16 + l15, quad);
      f32x4 ac = mfma1(Bb1, af2q, nt*16 + l15, quad);
      int col = nt*16 + l15;
      float gsv = gsR[nt];
      float s = 0.f, s2 = 0.f;
      #pragma unroll
      for (int r = 0; r < 4; ++r) {
        float v = ac[r] + gsv;
        g1[(long)(row0 + w*16 + quad*4 + r)*128 + col] = v;
        s += v; s2 = fmaf(v, v, s2);
      }
      s += __shfl_xor(s, 16); s += __shfl_xor(s, 32);
      s2 += __shfl_xor(s2, 16); s2 += __shfl_xor(s2, 32);
      sred[nt] = s; s2red[nt] = s2;
    }
  }
  __syncthreads();                       // S5: ALL LDS reads done -> arena free
  {
    #pragma unroll
    for (int nt = 0; nt < 8; ++nt) {
      int col = nt*16 + l15;
      #pragma unroll
      for (int r = 0; r < 4; ++r) {
        int row = w*16 + quad*4 + r;
        xsq[row*132 + col] = accv_q[nt][r] + bnl_q[nt*4 + r];
        xsk[row*132 + col] = accv_k[nt][r] + bnl_k[nt*4 + r];
      }
    }
  }
  #pragma unroll
  for (int it = 0; it < 4; ++it) { int idx = tid + it*256; pws[idx] = PW[idx]; }
  if (lane < 16) {
    #pragma unroll
    for (int nt = 0; nt < 8; ++nt) {
      ssum4[w*128 + nt*16 + l15] = sred[nt];
      ssq4[w*128 + nt*16 + l15] = s2red[nt];
    }
  }
  __syncthreads();                       // S6: xs + pws + scratch ready
  if (tid < 128) {
    float s = (ssum4[tid] + ssum4[128 + tid]) + (ssum4[256 + tid] + ssum4[384 + tid]);
    float s2 = (ssq4[tid] + ssq4[128 + tid]) + (ssq4[256 + tid] + ssq4[384 + tid]);
    atomicAdd(&statg1[tid], s);
    atomicAdd(&statg1[128 + tid], s2);
  }
  // rope: one sincos per (row, pair) applied to BOTH q and k (64 rows)
  #pragma unroll
  for (int it = 0; it < 16; ++it) {
    int idx = it*256 + tid;
    int r = idx >> 6, s = idx & 63;
    if (s < 63) {
      int a3 = s / 21, j = s - a3*21;
      int cr = a3*42 + j;
      float invf = exp2f((float)(2*j) * (-13.287712379549449f / 42.f));
      float ang = coord[(row0 + r)*3 + a3] * (2.0f * invf);
      float sn, co; sincosf(ang, &sn, &co);
      float fr = xsq[r*132 + cr], fi = xsq[r*132 + cr + 21];
      xsq[r*132 + cr]      = fr*co - fi*sn;
      xsq[r*132 + cr + 21] = fr*sn + fi*co;
      fr = xsk[r*132 + cr]; fi = xsk[r*132 + cr + 21];
      xsk[r*132 + cr]      = fr*co - fi*sn;
      xsk[r*132 + cr + 21] = fr*sn + fi*co;
    }
  }
  __syncthreads();                       // S7
  // projection: float4 LDS reads, 4 independent accumulators (64 rows x 2)
  #pragma unroll
  for (int it = 0; it < 4; ++it) {
    int idx = it*256 + tid;
    int mat = idx >> 9, r2 = (idx >> 3) & 63, g = idx & 7;
    const float* x2 = mat ? xsk : xsq;
    float a0 = 0.f, a1 = 0.f, a2 = 0.f, a3 = 0.f;
    #pragma unroll 8
    for (int i = 0; i < 128; i += 4) {
      float4 xv = *(const float4*)&x2[r2*132 + i];
      a0 = fmaf(xv.x, pws[(i+0)*8 + g], a0);
      a1 = fmaf(xv.y, pws[(i+1)*8 + g], a1);
      a2 = fmaf(xv.z, pws[(i+2)*8 + g], a2);
      a3 = fmaf(xv.w, pws[(i+3)*8 + g], a3);
    }
    float acc = (a0 + a1) + (a2 + a3) + (mat ? bw1[g] : 0.f);
    float* dst = mat ? kw : qw;
    dst[(long)(row0 + r2)*8 + g] = acc;
  }
}

// ---------------------------------------------------------------------------
// hstat_k: the hstat half of the old `mid` (body verbatim; 1024 blocks).
__global__ __launch_bounds__(256) void hstat_k(
    const float* __restrict__ kw, const float* __restrict__ qw,
    const int* __restrict__ ref, float* __restrict__ stath)
{
  __shared__ float red[256];
  int tid = threadIdx.x;
  long base = (long)blockIdx.x * 4096;
  float s = 0.f, sq = 0.f;
  for (int it = 0; it < 16; ++it) {
    long idx = base + it*256 + tid;
    int n = (int)(idx >> 7); int kk = (int)((idx >> 3) & 15); int g = (int)(idx & 7);
    int r = ref[n*16 + kk];
    float h = kw[(long)r*8 + g] - qw[(long)n*8 + g];
    s += h; sq = fmaf(h, h, sq);
  }
  red[tid] = s; __syncthreads();
  for (int d = 128; d >= 8; d >>= 1) { if (tid < d) red[tid] += red[tid + d]; __syncthreads(); }
  if (tid < 8) atomicAdd(&stath[tid], red[tid]);
  __syncthreads();
  red[tid] = sq; __syncthreads();
  for (int d = 128; d >= 8; d >>= 1) { if (tid < d) red[tid] += red[tid + d]; __syncthreads(); }
  if (tid < 8) atomicAdd(&stath[8 + tid], red[tid]);
}

// ---------------------------------------------------------------------------
// attn2: gate2 (verbatim mid math; gate kept in LDS, no global round-trip)
// fused with the attention body (verbatim math, iterated over 16 row-pairs;
// per-block constants hoisted). 1024 blocks x 32 rows.
__global__ __launch_bounds__(256) void attn2(
    const float* __restrict__ g1, const float* __restrict__ statg1,
    const float* __restrict__ ggm, const float* __restrict__ bng,
    const float* __restrict__ Wg2, const float* __restrict__ bg2,
    const float* __restrict__ qw, const float* __restrict__ kw,
    const float* __restrict__ stath,
    const float* __restrict__ gw, const float* __restrict__ bnw,
    const float* __restrict__ Ww2, const float* __restrict__ bw2,
    const int* __restrict__ ref, const float* __restrict__ v,
    float* __restrict__ out)
{
  __shared__ float gs[32][132];
  __shared__ float w2s[128][8];
  __shared__ float cA[128], cB[128];
  __shared__ float gt[32][8];
  __shared__ float sm1[2][16][9];
  __shared__ float sm2[2][16][9];
  __shared__ int   smr[2][16];
  int tid = threadIdx.x;
  int row0 = blockIdx.x * 32;
  // ---- gate2 (verbatim from mid)
  #pragma unroll
  for (int it = 0; it < 4; ++it) { int idx = tid + it*256; w2s[idx >> 3][idx & 7] = Wg2[idx]; }
  if (tid < 128) {
    const float invn = 1.f / 32768.f;
    float m = statg1[tid]*invn, vv = fmaf(-m, m, statg1[128 + tid]*invn);
    float a = rsqrtf(vv + 1e-5f) * ggm[tid];
    cA[tid] = a; cB[tid] = fmaf(-m, a, bng[tid]);
  }
  #pragma unroll
  for (int it = 0; it < 4; ++it) {
    int idx = tid + it*256; int r = idx >> 5, cq = idx & 31;
    *(float4*)&gs[r][cq*4] = *(const float4*)&g1[(long)(row0 + r)*128 + cq*4];
  }
  __syncthreads();
  {
    int r = tid >> 3, g = tid & 7;
    float acc = bg2[g];
    #pragma unroll 8
    for (int c2 = 0; c2 < 128; ++c2) {
      float act = fmaxf(0.f, fmaf(gs[r][c2], cA[c2], cB[c2]));
      acc = fmaf(act, w2s[c2][g], acc);
    }
    gt[r][g] = 1.f / (1.f + expf(-acc));
  }
  // ---- attention consts hoisted (identical values to old per-block loads)
  int rh = tid >> 7, t = tid & 127;
  int kk = t >> 3, g = t & 7;
  const float invnk = 1.f / 524288.f;
  float m0 = stath[g]*invnk, v0 = fmaf(-m0, m0, stath[8 + g]*invnk);
  float aw = rsqrtf(v0 + 1e-5f) * gw[g];
  float bw = fmaf(-m0, aw, bnw[g]);
  float w2r[8];
  #pragma unroll
  for (int g2 = 0; g2 < 8; ++g2) w2r[g2] = Ww2[g2*8 + g];
  float bw2g = bw2[g];
  __syncthreads();                 // gt ready; gs dead
  for (int itr = 0; itr < 16; ++itr) {
    int nl = itr*2 + rh;
    int n = row0 + nl;
    if (t < 16) smr[rh][t] = ref[n*16 + t];
    __syncthreads();
    int rr = smr[rh][kk];
    float h = kw[(long)rr*8 + g] - qw[(long)n*8 + g];
    sm1[rh][kk][g] = fmaxf(0.f, fmaf(h, aw, bw));
    __syncthreads();
    float acc = bw2g;
    #pragma unroll
    for (int g2 = 0; g2 < 8; ++g2) acc = fmaf(sm1[rh][kk][g2], w2r[g2], acc);
    float refined = acc * (1.f + gt[nl][g]);
    sm2[rh][kk][g] = refined;
    __syncthreads();
    float mx = -1e30f;
    #pragma unroll
    for (int k2 = 0; k2 < 16; ++k2) mx = fmaxf(mx, sm2[rh][k2][g]);
    float e = expf(refined - mx);
    sm1[rh][kk][g] = e;
    __syncthreads();
    float ssum = 0.f;
    #pragma unroll
    for (int k2 = 0; k2 < 16; ++k2) ssum += sm1[rh][k2][g];
    float mask = ((rr + 1) > 0) ? 1.f : (((rr + 1) == 0) ? 0.f : -1.f);
    float attn = e / ssum * mask;
    sm2[rh][kk][g] = attn;
    __syncthreads();
    float o = 0.f;
    #pragma unroll
    for (int k2 = 0; k2 < 16; ++k2) {
      o = fmaf(v[(long)smr[rh][k2]*128 + t], sm2[rh][k2][t >> 4], o);
    }
    out[(long)n*128 + t] = o;
    __syncthreads();               // fence before smr/sm reuse next iteration
  }
}

// ---------------------------------------------------------------------------
extern "C" void kernel_launch(void* const* d_in, const int* in_sizes, int n_in,
                              void* d_out, int out_size, void* d_ws, size_t ws_size,
                              hipStream_t stream)
{
  const float* feat  = (const float*)d_in[0];
  const float* coord = (const float*)d_in[1];
  const int*   ref   = (const int*)d_in[2];
  const float* Wq  = (const float*)d_in[4];
  const float* bq  = (const float*)d_in[5];
  const float* gq  = (const float*)d_in[6];
  const float* bnq = (const float*)d_in[7];
  const float* Wk  = (const float*)d_in[8];
  const float* bk  = (const float*)d_in[9];
  const float* gk  = (const float*)d_in[10];
  const float* bnk = (const float*)d_in[11];
  const float* Wv  = (const float*)d_in[12];
  const float* bv  = (const float*)d_in[13];
  const float* Sp  = (const float*)d_in[14];
  const float* Ww1 = (const float*)d_in[15];
  const float* bw1 = (const float*)d_in[16];
  const float* gw  = (const float*)d_in[17];
  const float* bnw = (const float*)d_in[18];
  const float* Ww2 = (const float*)d_in[19];
  const float* bw2 = (const float*)d_in[20];
  const float* Wg1 = (const float*)d_in[21];
  const float* bg1 = (const float*)d_in[22];
  const float* ggm = (const float*)d_in[23];
  const float* bng = (const float*)d_in[24];
  const float* Wg2 = (const float*)d_in[25];
  const float* bg2 = (const float*)d_in[26];
  float* out = (float*)d_out;

  float* W = (float*)d_ws;
  float* PW = W + OF_PW;
  short* WqT   = (short*)(W + OF_WQT);
  short* WkT   = (short*)(W + OF_WKT);
  short* WvT   = (short*)(W + OF_WVT);
  short* Wg1T  = (short*)(W + OF_WG1T);
  short* PTmIT = (short*)(W + OF_PTMIT);
  float* G1 = W + OF_G1;
  float* Vv = W + OF_V;

  // 1: Cayley via per-column Neumann + weight bf16 transposes + stat zeroing
  cayley<<<81, 256, 0, stream>>>(Sp, Ww1, Wq, Wk, Wv, Wg1,
                                 WqT, WkT, WvT, Wg1T, PTmIT, PW, W + OF_STATQ);
  // 2: q/k GEMM -> stats/minmax; v GEMM -> store
  qkv_mfma<<<512, 256, 0, stream>>>(feat, WqT, WkT, WvT, bq, bk, bv, Vv,
                                    W + OF_STATQ, W + OF_STATK,
                                    (unsigned*)(W + OF_UMAXP), (unsigned*)(W + OF_UMAXN));
  // 2b: hoisted per-segment gate vector
  gprep<<<4, 128, 0, stream>>>(W + OF_STATQ, gq, bnq, bq,
                               (const unsigned*)(W + OF_UMAXP),
                               (const unsigned*)(W + OF_UMAXN),
                               Wg1, bg1, W + OF_GSG);
  // 3: recompute lin + BN + rotate + rope + project + g1(+stats)
  rqkw<<<512, 256, 0, stream>>>(feat, WqT, WkT, PTmIT, Wg1T, coord,
                                bq, bk,
                                W + OF_STATQ, W + OF_STATK,
                                gq, bnq, gk, bnk,
                                W + OF_GSG, PW, bw1,
                                W + OF_QW, W + OF_KW, G1, W + OF_STATG1);
  // 4: h statistics (global over all (n,k))
  hstat_k<<<1024, 256, 0, stream>>>(W + OF_KW, W + OF_QW, ref, W + OF_STATH);
  // 5: gate2 (in-LDS) + final attention + V gather, 32 rows/block
  attn2<<<1024, 256, 0, stream>>>(G1, W + OF_STATG1, ggm, bng, Wg2, bg2,
                                  W + OF_QW, W + OF_KW, W + OF_STATH,
                                  gw, bnw, Ww2, bw2, ref, Vv, out);
}

// Round 13
// 289.442 us; speedup vs baseline: 1.0227x; 1.0227x over previous
//
#include <hip/hip_runtime.h>
#include <math.h>

// Problem constants (fixed shapes)
#define N_PTS 32768
#define C_DIM 128
#define K_NB  16
#define G_DIM 8

// Workspace float offsets
#define OF_PW     0          // 128*8  P @ Ww1 (fp32)
#define OF_STATQ  1024       // 256 (sum, sumsq) of q_lin
#define OF_STATK  1280       // 256
#define OF_STATG1 1536       // 256
#define OF_STATH  1792       // 16
#define OF_UMAXP  1808       // 4*128 encoded max(q_lin raw) per seg
#define OF_UMAXN  2320       // 4*128 encoded max(-q_lin raw) per seg (zero region = 1024..2832)
#define OF_GSG    2832       // 4*128 precomputed gate-seg vector (gprep)
// bf16 [n][k] operands, 16384 shorts = 8192 floats each
#define OF_WQT    4096
#define OF_WKT    12288
#define OF_WVT    20480
#define OF_WG1T   28672
#define OF_PTMIT  36864
#define OF_QW     65536      // N*8
#define OF_KW     327680     // N*8
#define OF_GATE   589824     // N*8 (unused — gate lives in LDS)
#define OF_G1     1048576    // N*128
#define OF_V      5242880    // N*128 region; round 13: V stored as bf16 (N*128 shorts)

typedef short bf16x8 __attribute__((ext_vector_type(8)));
typedef float f32x4  __attribute__((ext_vector_type(4)));

#define LSTR 136   // bf16 LDS row stride (272 B) — cayley tiles

__device__ __forceinline__ unsigned f2bf(float f) {
  unsigned u = __float_as_uint(f);
  return (u + 0x7fffu + ((u >> 16) & 1u)) >> 16;
}
__device__ __forceinline__ float bf2f(short s) {
  return __uint_as_float(((unsigned)(unsigned short)s) << 16);
}
__device__ __forceinline__ unsigned fenc(float f) {
  unsigned b = __float_as_uint(f);
  return (b & 0x80000000u) ? ~b : (b | 0x80000000u);
}
__device__ __forceinline__ float fdec(unsigned u) {
  unsigned b = (u & 0x80000000u) ? (u & 0x7fffffffu) : ~u;
  return __uint_as_float(b);
}
__device__ __forceinline__ bf16x8 pack_bf8(float4 a, float4 b) {
  bf16x8 r;
  r[0] = (short)f2bf(a.x); r[1] = (short)f2bf(a.y);
  r[2] = (short)f2bf(a.z); r[3] = (short)f2bf(a.w);
  r[4] = (short)f2bf(b.x); r[5] = (short)f2bf(b.y);
  r[6] = (short)f2bf(b.z); r[7] = (short)f2bf(b.w);
  return r;
}

// async 16B global -> LDS (no VGPR round-trip, drained by __syncthreads)
__device__ __forceinline__ void g2l16(const void* g, void* l) {
  __builtin_amdgcn_global_load_lds(
      (const __attribute__((address_space(1))) void*)g,
      (__attribute__((address_space(3))) void*)l, 16, 0, 0);
}

// Async-stage a [128][128] bf16 tile (32 KB) into LINEAR LDS.
// Pre-swizzled global source (involution byte ^ ((row&7)<<4)) so the
// swizzled ds_reads in mfma1 are bank-balanced. Validated rounds 3-12.
__device__ __forceinline__ void stage_async(short* dst, const short* __restrict__ src, int tid) {
  int lane = tid & 63, wv = tid >> 6;
  #pragma unroll
  for (int it = 0; it < 8; ++it) {
    int chunk = it*256 + wv*64;            // wave-uniform 16B-chunk base
    int D = (chunk + lane)*16;             // this lane's linear LDS byte offset
    int gs = D ^ (((D >> 8) & 7) << 4);    // inverse (== forward) swizzle
    g2l16((const char*)src + gs, (char*)dst + chunk*16);
  }
}

// One 16x16x32 MFMA column-tile over swizzle-staged LDS B: returns af @ B
// for output col group; caller passes row = nt*16 + l15.
__device__ __forceinline__ f32x4 mfma1(const short* Bb, const bf16x8* a4, int row, int quad) {
  f32x4 ac = {0.f, 0.f, 0.f, 0.f};
  int sx = (row & 7) << 4;
  #pragma unroll
  for (int ks = 0; ks < 4; ++ks) {
    const char* p = (const char*)Bb + (((row*256) + ks*64 + quad*16) ^ sx);
    ac = __builtin_amdgcn_mfma_f32_16x16x32_bf16(a4[ks], *(const bf16x8*)p, ac, 0, 0, 0);
  }
  return ac;
}

// ---------------------------------------------------------------------------
// cayley: unchanged from round 8 (coalesced staging, validated; outputs
// bitwise identical).
__global__ __launch_bounds__(256) void cayley(const float* __restrict__ Sp,
    const float* __restrict__ Ww1,
    const float* __restrict__ Wq, const float* __restrict__ Wk,
    const float* __restrict__ Wv, const float* __restrict__ Wg1,
    short* __restrict__ WqT, short* __restrict__ WkT,
    short* __restrict__ WvT, short* __restrict__ Wg1T,
    short* __restrict__ PTmIT, float* __restrict__ PW,
    float* __restrict__ statz)
{
  __shared__ __align__(16) short Ssh[128*LSTR];
  __shared__ float x0[128], x1[128];
  int bx = blockIdx.x, tid = threadIdx.x;
  if (bx >= 64) {
    if (bx < 80) {
      int idx = bx - 64, widx = idx >> 2, qr = idx & 3;
      const float* src = (widx == 0) ? Wq : (widx == 1) ? Wk : (widx == 2) ? Wv : Wg1;
      short* dst = (widx == 0) ? WqT : (widx == 1) ? WkT : (widx == 2) ? WvT : Wg1T;
      const float4* s4 = (const float4*)src;
      short* T = Ssh;                    // [128][40] shorts: 80B rows, 16B-aligned
      #pragma unroll
      for (int it = 0; it < 4; ++it) {
        int q = it*256 + tid; int kloc = q >> 5, n4 = q & 31;
        float4 v = s4[(qr*32 + kloc)*32 + n4];
        T[(n4*4+0)*40 + kloc] = (short)f2bf(v.x);
        T[(n4*4+1)*40 + kloc] = (short)f2bf(v.y);
        T[(n4*4+2)*40 + kloc] = (short)f2bf(v.z);
        T[(n4*4+3)*40 + kloc] = (short)f2bf(v.w);
      }
      __syncthreads();
      #pragma unroll
      for (int it = 0; it < 2; ++it) {
        int i2 = it*256 + tid;           // 512 chunks of 8 shorts (128 rows x 4)
        int n = i2 >> 2, part = i2 & 3;
        uint4 val = *(const uint4*)&T[n*40 + part*8];
        *(uint4*)&dst[n*128 + qr*32 + part*8] = val;
      }
    } else {
      #pragma unroll
      for (int it = 0; it < 8; ++it) {
        int idx = it*256 + tid;
        if (idx < 1808) statz[idx] = 0.f;
      }
    }
    return;
  }
  int c0 = bx*2, c1 = c0 + 1;
  // stage antisymmetrized S: coalesced row reads; mirror for lower triangle
  {
    const float4* s4 = (const float4*)Sp;
    #pragma unroll
    for (int it = 0; it < 16; ++it) {
      int idx = it*256 + tid;            // 4096 float4 chunks, row-major
      int i = idx >> 5, j0 = (idx & 31) * 4;
      float4 v = s4[idx];
      #pragma unroll
      for (int u = 0; u < 4; ++u) {
        int j = j0 + u;
        float val = (&v.x)[u];
        if (j > i) {
          unsigned b = f2bf(val);
          Ssh[i*LSTR + j] = (short)b;                    // upper:  bf16(v)
          Ssh[j*LSTR + i] = (short)(b ^ 0x8000u);        // lower: -bf16(v) == bf16(-v)
        } else if (j == i) {
          Ssh[i*LSTR + j] = 0;                           // diagonal
        }
      }
    }
  }
  if (tid < 128) {
    x0[tid] = (tid == c0) ? 1.f : 0.f;
    x1[tid] = (tid == c1) ? 1.f : 0.f;
  }
  __syncthreads();
  int i = tid >> 1, h = tid & 1;
  const short* srow = &Ssh[i*LSTR + h*64];
  for (int t = 0; t < 16; ++t) {
    float a0 = 0.f, a1 = 0.f;
    #pragma unroll
    for (int jq = 0; jq < 16; ++jq) {
      short4 sv = *(const short4*)&srow[jq*4];
      #pragma unroll
      for (int u = 0; u < 4; ++u) {
        float s = bf2f((&sv.x)[u]);
        int j = h*64 + jq*4 + u;
        a0 = fmaf(s, x0[j], a0);
        a1 = fmaf(s, x1[j], a1);
      }
    }
    a0 += __shfl_xor(a0, 1);
    a1 += __shfl_xor(a1, 1);
    __syncthreads();
    if (h == 0) {
      x0[i] = a0 + ((i == c0) ? 1.f : 0.f);
      x1[i] = a1 + ((i == c1) ? 1.f : 0.f);
    }
    __syncthreads();
  }
  if (tid < 128) {
    PTmIT[c0*128 + tid] = (short)f2bf(2.f*x0[tid] - ((tid == c0) ? 2.f : 0.f));
  } else {
    int t = tid - 128;
    PTmIT[c1*128 + t] = (short)f2bf(2.f*x1[t] - ((t == c1) ? 2.f : 0.f));
  }
  if (tid < 16) {
    int cc = tid >> 3, g = tid & 7;
    const float* xv = cc ? x1 : x0;
    int c = cc ? c1 : c0;
    float acc = 0.f;
    #pragma unroll 8
    for (int j = 0; j < 128; ++j) acc = fmaf(xv[j], Ww1[j*8 + g], acc);
    PW[c*8 + g] = 2.f*acc - Ww1[c*8 + g];
  }
}

// ---------------------------------------------------------------------------
// qkv: round-9 structure; ROUND 13: V stored as bf16 (halves the V table to
// 8 MB -> halves attn2's gather traffic and qkv's V writes).
__global__ __launch_bounds__(256, 2) void qkv_mfma(const float* __restrict__ feat,
    const short* __restrict__ WqT, const short* __restrict__ WkT, const short* __restrict__ WvT,
    const float* __restrict__ bq, const float* __restrict__ bk, const float* __restrict__ bv,
    short* __restrict__ Vb,
    float* __restrict__ statq, float* __restrict__ statk,
    unsigned* __restrict__ umaxp, unsigned* __restrict__ umaxn)
{
  __shared__ __align__(16) short Bb0[128*128];   // 32768 B
  __shared__ __align__(16) short Bb1[128*128];   // 32768 B
  __shared__ float ssum[2][128], ssq[2][128];
  __shared__ unsigned ump[128], umn[128];
  int tid = threadIdx.x, row0 = blockIdx.x * 64, seg = row0 >> 13;
  int lane = tid & 63, w = tid >> 6, l15 = lane & 15, quad = lane >> 4;
  stage_async(Bb0, WqT, tid);                  // async, in flight during setup
  if (tid < 128) {
    ssum[0][tid] = 0.f; ssum[1][tid] = 0.f;
    ssq[0][tid] = 0.f;  ssq[1][tid] = 0.f;
    ump[tid] = 0u; umn[tid] = 0u;
  }
  // A-fragments: direct from feat (read once, used by all 3 GEMMs)
  bf16x8 af[4];
  {
    long rbase = (long)(row0 + w*16 + l15) * 128;
    #pragma unroll
    for (int ks = 0; ks < 4; ++ks) {
      int c0 = ks*32 + quad*8;
      float4 v0 = *(const float4*)&feat[rbase + c0];
      float4 v1 = *(const float4*)&feat[rbase + c0 + 4];
      af[ks] = pack_bf8(v0, v1);
    }
  }
  __syncthreads();                       // S0: Bb0 staged, stats init
  stage_async(Bb1, WkT, tid);            // flies during GEMM-q
  // ---- q: GEMM + stats + raw minmax
  {
    #pragma unroll
    for (int nt = 0; nt < 8; ++nt) {
      f32x4 ac = mfma1(Bb0, af, nt*16 + l15, quad);
      int col = nt*16 + l15;
      float bb = bq[col];
      float s = 0.f, s2 = 0.f, mx = -1e30f, mn = 1e30f;
      #pragma unroll
      for (int r = 0; r < 4; ++r) {
        float raw = ac[r];
        float v = raw + bb;
        s += v; s2 = fmaf(v, v, s2);
        mx = fmaxf(mx, raw); mn = fminf(mn, raw);   // raw minmax (bias folded later)
      }
      s += __shfl_xor(s, 16); s += __shfl_xor(s, 32);
      s2 += __shfl_xor(s2, 16); s2 += __shfl_xor(s2, 32);
      mx = fmaxf(mx, __shfl_xor(mx, 16)); mx = fmaxf(mx, __shfl_xor(mx, 32));
      mn = fminf(mn, __shfl_xor(mn, 16)); mn = fminf(mn, __shfl_xor(mn, 32));
      if (lane < 16) {
        atomicAdd(&ssum[0][col], s); atomicAdd(&ssq[0][col], s2);
        atomicMax(&ump[col], fenc(mx)); atomicMax(&umn[col], fenc(-mn));
      }
    }
  }
  __syncthreads();                       // S1: Bb1 staged, Bb0 reads done
  stage_async(Bb0, WvT, tid);            // flies during GEMM-k
  // ---- k: GEMM + stats
  {
    #pragma unroll
    for (int nt = 0; nt < 8; ++nt) {
      f32x4 ac = mfma1(Bb1, af, nt*16 + l15, quad);
      int col = nt*16 + l15;
      float bb = bk[col];
      float s = 0.f, s2 = 0.f;
      #pragma unroll
      for (int r = 0; r < 4; ++r) {
        float v = ac[r] + bb;
        s += v; s2 = fmaf(v, v, s2);
      }
      s += __shfl_xor(s, 16); s += __shfl_xor(s, 32);
      s2 += __shfl_xor(s2, 16); s2 += __shfl_xor(s2, 32);
      if (lane < 16) { atomicAdd(&ssum[1][col], s); atomicAdd(&ssq[1][col], s2); }
    }
  }
  __syncthreads();                       // S2: Bb0(Wv) staged, Bb1 reads done
  // ---- v: GEMM + bf16 store (round-13 precision change, see header note)
  {
    #pragma unroll
    for (int nt = 0; nt < 8; ++nt) {
      f32x4 ac = mfma1(Bb0, af, nt*16 + l15, quad);
      int col = nt*16 + l15;
      float bb = bv[col];
      #pragma unroll
      for (int r = 0; r < 4; ++r)
        Vb[(long)(row0 + w*16 + quad*4 + r)*128 + col] = (short)f2bf(ac[r] + bb);
    }
  }
  __syncthreads();                       // S3: LDS stats complete
  if (tid < 128) {
    atomicAdd(&statq[tid], ssum[0][tid]); atomicAdd(&statq[128 + tid], ssq[0][tid]);
    atomicAdd(&statk[tid], ssum[1][tid]); atomicAdd(&statk[128 + tid], ssq[1][tid]);
    atomicMax(&umaxp[seg*128 + tid], ump[tid]);
    atomicMax(&umaxn[seg*128 + tid], umn[tid]);
  }
}

// ---------------------------------------------------------------------------
// gprep: hoisted per-segment gate vector (unchanged, validated round 7).
__global__ __launch_bounds__(128) void gprep(
    const float* __restrict__ statq,
    const float* __restrict__ gq, const float* __restrict__ bnq,
    const float* __restrict__ bq,
    const unsigned* __restrict__ umaxp, const unsigned* __restrict__ umaxn,
    const float* __restrict__ Wg1, const float* __restrict__ bg1,
    float* __restrict__ gsgO)
{
  __shared__ float gml[128];
  int s = blockIdx.x, tid = threadIdx.x;   // 128 threads
  const float invn = 1.f / 32768.f;
  {
    float m = statq[tid]*invn, vv = fmaf(-m, m, statq[128 + tid]*invn);
    float a = rsqrtf(vv + 1e-5f) * gq[tid];
    float b = fmaf(-m, a, bnq[tid]);
    float cb2 = fmaf(a, bq[tid], b);
    float mx = fdec(umaxp[s*128 + tid]);
    float mn = -fdec(umaxn[s*128 + tid]);
    gml[tid] = fmaxf(0.f, fmaxf(fmaf(a, mx, cb2), fmaf(a, mn, cb2)));
  }
  __syncthreads();
  float acc = bg1[tid];
  #pragma unroll 8
  for (int j = 0; j < 128; ++j)
    acc = fmaf(gml[j], Wg1[(128 + j)*128 + tid], acc);
  gsgO[s*128 + tid] = acc;
}

// ---------------------------------------------------------------------------
// rqkw: round-9 validated form (unchanged). 64-row blocks x 512, ALL 4
// waves in EVERY GEMM; single bn tile time-shared; per-wave stat scratch.
__global__ __launch_bounds__(256, 2) void rqkw(
    const float* __restrict__ feat,
    const short* __restrict__ WqT, const short* __restrict__ WkT,
    const short* __restrict__ PTmIT, const short* __restrict__ Wg1T,
    const float* __restrict__ coord,
    const float* __restrict__ bq, const float* __restrict__ bk,
    const float* __restrict__ statq, const float* __restrict__ statk,
    const float* __restrict__ gq, const float* __restrict__ bnq,
    const float* __restrict__ gk, const float* __restrict__ bnk,
    const float* __restrict__ gsgG,
    const float* __restrict__ PW, const float* __restrict__ bw1,
    float* __restrict__ qw, float* __restrict__ kw,
    float* __restrict__ g1, float* __restrict__ statg1)
{
  __shared__ __align__(16) char arena[81920];
  short* Bb0  = (short*)arena;
  short* Bb1  = (short*)(arena + 32768);
  char*  bnS  = arena + 65536;               // 16384 B (64 rows x 256 B)
  float* xsq  = (float*)arena;
  float* xsk  = (float*)(arena + 33792);
  float* pws  = (float*)(arena + 67584);
  float* ssum4 = (float*)(arena + 71680);    // [4][128]
  float* ssq4  = (float*)(arena + 73728);    // [4][128]
  int tid = threadIdx.x, row0 = blockIdx.x * 64, seg = row0 >> 13;
  int lane = tid & 63, w = tid >> 6, l15 = lane & 15, quad = lane >> 4;
  stage_async(Bb0, WqT, tid);            // both weight tiles in flight
  stage_async(Bb1, WkT, tid);            // during all setup below
  bf16x8 af[4];
  {
    long rbase = (long)(row0 + w*16 + l15) * 128;
    #pragma unroll
    for (int ks = 0; ks < 4; ++ks) {
      int c0 = ks*32 + quad*8;
      float4 v0 = *(const float4*)&feat[rbase + c0];
      float4 v1 = *(const float4*)&feat[rbase + c0 + 4];
      af[ks] = pack_bf8(v0, v1);
    }
  }
  float caRq[8], cbRq[8], caRk[8], cbRk[8];
  {
    const float invn = 1.f / 32768.f;
    #pragma unroll
    for (int nt = 0; nt < 8; ++nt) {
      int col = nt*16 + l15;
      float m = statq[col]*invn, vv = fmaf(-m, m, statq[128 + col]*invn);
      float a = rsqrtf(vv + 1e-5f) * gq[col];
      float b = fmaf(-m, a, bnq[col]);
      caRq[nt] = a; cbRq[nt] = fmaf(a, bq[col], b);
      m = statk[col]*invn; vv = fmaf(-m, m, statk[128 + col]*invn);
      a = rsqrtf(vv + 1e-5f) * gk[col];
      b = fmaf(-m, a, bnk[col]);
      caRk[nt] = a; cbRk[nt] = fmaf(a, bk[col], b);
    }
  }
  float gsR[8];
  #pragma unroll
  for (int nt = 0; nt < 8; ++nt)
    gsR[nt] = gsgG[seg*128 + nt*16 + l15];
  __syncthreads();                       // S0: Bb0(Wq)+Bb1(Wk) staged
  float bnl_q[32], bnl_k[32];
  // ---- GEMM1q (ALL waves, Bb0) + BN -> bnS tile + bnl_q regs
  {
    #pragma unroll
    for (int nt = 0; nt < 8; ++nt) {
      f32x4 ac = mfma1(Bb0, af, nt*16 + l15, quad);
      int col = nt*16 + l15;
      float A = caRq[nt], B = cbRq[nt];
      #pragma unroll
      for (int r = 0; r < 4; ++r) {
        float v = fmaxf(0.f, fmaf(A, ac[r], B));
        bnl_q[nt*4 + r] = v;
        int row = w*16 + quad*4 + r;
        int ba = (row*256 + col*2) ^ ((row & 7) << 4);
        *(short*)(bnS + ba) = (short)f2bf(v);
      }
    }
  }
  __syncthreads();                       // S1: Bb0(Wq) reads done; bnS(q) done
  stage_async(Bb0, PTmIT, tid);          // hidden under GEMM1k
  // ---- GEMM1k (ALL waves, Bb1) -> bnl_k regs only
  {
    #pragma unroll
    for (int nt = 0; nt < 8; ++nt) {
      f32x4 ac = mfma1(Bb1, af, nt*16 + l15, quad);
      float A = caRk[nt], B = cbRk[nt];
      #pragma unroll
      for (int r = 0; r < 4; ++r)
        bnl_k[nt*4 + r] = fmaxf(0.f, fmaf(A, ac[r], B));
    }
  }
  __syncthreads();                       // S2: Bb0(PTmI) ready; Bb1 reads done
  stage_async(Bb1, Wg1T, tid);           // hidden under GEMM2q
  bf16x8 af2q[4];
  {
    int rowA = w*16 + l15, sx2 = (rowA & 7) << 4;
    #pragma unroll
    for (int ks = 0; ks < 4; ++ks)
      af2q[ks] = *(const bf16x8*)(bnS + ((rowA*256 + ks*64 + quad*16) ^ sx2));
  }
  // ---- GEMM2q: rotation for q (ALL waves, Bb0 = PTmI)
  f32x4 accv_q[8];
  #pragma unroll
  for (int nt = 0; nt < 8; ++nt)
    accv_q[nt] = mfma1(Bb0, af2q, nt*16 + l15, quad);
  __syncthreads();                       // S3: af2q reads done; Bb1(Wg1) ready
  // ---- rewrite bnS with bn(k)
  {
    #pragma unroll
    for (int nt = 0; nt < 8; ++nt) {
      int col = nt*16 + l15;
      #pragma unroll
      for (int r = 0; r < 4; ++r) {
        int row = w*16 + quad*4 + r;
        int ba = (row*256 + col*2) ^ ((row & 7) << 4);
        *(short*)(bnS + ba) = (short)f2bf(bnl_k[nt*4 + r]);
      }
    }
  }
  __syncthreads();                       // S4: bnS(k) complete
  bf16x8 af2k[4];
  {
    int rowA = w*16 + l15, sx2 = (rowA & 7) << 4;
    #pragma unroll
    for (int ks = 0; ks < 4; ++ks)
      af2k[ks] = *(const bf16x8*)(bnS + ((rowA*256 + ks*64 + quad*16) ^ sx2));
  }
  // ---- GEMM2k (Bb0 = PTmI) + GEMM3 (Bb1 = Wg1, af2q) with reg-held stats
  f32x4 accv_k[8];
  float sred[8], s2red[8];
  {
    #pragma unroll
    for (int nt = 0; nt < 8; ++nt) {
      accv_k[nt] = mfma1(Bb0, af2k, nt*16 + l15, quad);
      f32x4 ac = mfma1(Bb1, af2q, nt*16 + l15, quad);
      int col = nt*16 + l15;
      float gsv = gsR[nt];
      float s = 0.f, s2 = 0.f;
      #pragma unroll
      for (int r = 0; r < 4; ++r) {
        float v = ac[r] + gsv;
        g1[(long)(row0 + w*16 + quad*4 + r)*128 + col] = v;
        s += v; s2 = fmaf(v, v, s2);
      }
      s += __shfl_xor(s, 16); s += __shfl_xor(s, 32);
      s2 += __shfl_xor(s2, 16); s2 += __shfl_xor(s2, 32);
      sred[nt] = s; s2red[nt] = s2;
    }
  }
  __syncthreads();                       // S5: ALL LDS reads done -> arena free
  {
    #pragma unroll
    for (int nt = 0; nt < 8; ++nt) {
      int col = nt*16 + l15;
      #pragma unroll
      for (int r = 0; r < 4; ++r) {
        int row = w*16 + quad*4 + r;
        xsq[row*132 + col] = accv_q[nt][r] + bnl_q[nt*4 + r];
        xsk[row*132 + col] = accv_k[nt][r] + bnl_k[nt*4 + r];
      }
    }
  }
  #pragma unroll
  for (int it = 0; it < 4; ++it) { int idx = tid + it*256; pws[idx] = PW[idx]; }
  if (lane < 16) {
    #pragma unroll
    for (int nt = 0; nt < 8; ++nt) {
      ssum4[w*128 + nt*16 + l15] = sred[nt];
      ssq4[w*128 + nt*16 + l15] = s2red[nt];
    }
  }
  __syncthreads();                       // S6: xs + pws + scratch ready
  if (tid < 128) {
    float s = (ssum4[tid] + ssum4[128 + tid]) + (ssum4[256 + tid] + ssum4[384 + tid]);
    float s2 = (ssq4[tid] + ssq4[128 + tid]) + (ssq4[256 + tid] + ssq4[384 + tid]);
    atomicAdd(&statg1[tid], s);
    atomicAdd(&statg1[128 + tid], s2);
  }
  // rope: one sincos per (row, pair) applied to BOTH q and k (64 rows)
  #pragma unroll
  for (int it = 0; it < 16; ++it) {
    int idx = it*256 + tid;
    int r = idx >> 6, s = idx & 63;
    if (s < 63) {
      int a3 = s / 21, j = s - a3*21;
      int cr = a3*42 + j;
      float invf = exp2f((float)(2*j) * (-13.287712379549449f / 42.f));
      float ang = coord[(row0 + r)*3 + a3] * (2.0f * invf);
      float sn, co; sincosf(ang, &sn, &co);
      float fr = xsq[r*132 + cr], fi = xsq[r*132 + cr + 21];
      xsq[r*132 + cr]      = fr*co - fi*sn;
      xsq[r*132 + cr + 21] = fr*sn + fi*co;
      fr = xsk[r*132 + cr]; fi = xsk[r*132 + cr + 21];
      xsk[r*132 + cr]      = fr*co - fi*sn;
      xsk[r*132 + cr + 21] = fr*sn + fi*co;
    }
  }
  __syncthreads();                       // S7
  // projection: float4 LDS reads, 4 independent accumulators (64 rows x 2)
  #pragma unroll
  for (int it = 0; it < 4; ++it) {
    int idx = it*256 + tid;
    int mat = idx >> 9, r2 = (idx >> 3) & 63, g = idx & 7;
    const float* x2 = mat ? xsk : xsq;
    float a0 = 0.f, a1 = 0.f, a2 = 0.f, a3 = 0.f;
    #pragma unroll 8
    for (int i = 0; i < 128; i += 4) {
      float4 xv = *(const float4*)&x2[r2*132 + i];
      a0 = fmaf(xv.x, pws[(i+0)*8 + g], a0);
      a1 = fmaf(xv.y, pws[(i+1)*8 + g], a1);
      a2 = fmaf(xv.z, pws[(i+2)*8 + g], a2);
      a3 = fmaf(xv.w, pws[(i+3)*8 + g], a3);
    }
    float acc = (a0 + a1) + (a2 + a3) + (mat ? bw1[g] : 0.f);
    float* dst = mat ? kw : qw;
    dst[(long)(row0 + r2)*8 + g] = acc;
  }
}

// ---------------------------------------------------------------------------
// hstat_k: the hstat reduction (body verbatim; 1024 blocks).
__global__ __launch_bounds__(256) void hstat_k(
    const float* __restrict__ kw, const float* __restrict__ qw,
    const int* __restrict__ ref, float* __restrict__ stath)
{
  __shared__ float red[256];
  int tid = threadIdx.x;
  long base = (long)blockIdx.x * 4096;
  float s = 0.f, sq = 0.f;
  for (int it = 0; it < 16; ++it) {
    long idx = base + it*256 + tid;
    int n = (int)(idx >> 7); int kk = (int)((idx >> 3) & 15); int g = (int)(idx & 7);
    int r = ref[n*16 + kk];
    float h = kw[(long)r*8 + g] - qw[(long)n*8 + g];
    s += h; sq = fmaf(h, h, sq);
  }
  red[tid] = s; __syncthreads();
  for (int d = 128; d >= 8; d >>= 1) { if (tid < d) red[tid] += red[tid + d]; __syncthreads(); }
  if (tid < 8) atomicAdd(&stath[tid], red[tid]);
  __syncthreads();
  red[tid] = sq; __syncthreads();
  for (int d = 128; d >= 8; d >>= 1) { if (tid < d) red[tid] += red[tid + d]; __syncthreads(); }
  if (tid < 8) atomicAdd(&stath[8 + tid], red[tid]);
}

// ---------------------------------------------------------------------------
// attn2: gate2 (in-LDS) + attention body. ROUND 13: V gather reads bf16
// (halves the dominant 131 MB fetch stream). All other math verbatim.
__global__ __launch_bounds__(256) void attn2(
    const float* __restrict__ g1, const float* __restrict__ statg1,
    const float* __restrict__ ggm, const float* __restrict__ bng,
    const float* __restrict__ Wg2, const float* __restrict__ bg2,
    const float* __restrict__ qw, const float* __restrict__ kw,
    const float* __restrict__ stath,
    const float* __restrict__ gw, const float* __restrict__ bnw,
    const float* __restrict__ Ww2, const float* __restrict__ bw2,
    const int* __restrict__ ref, const short* __restrict__ vb,
    float* __restrict__ out)
{
  __shared__ float gs[32][132];
  __shared__ float w2s[128][8];
  __shared__ float cA[128], cB[128];
  __shared__ float gt[32][8];
  __shared__ float sm1[2][16][9];
  __shared__ float sm2[2][16][9];
  __shared__ int   smr[2][16];
  int tid = threadIdx.x;
  int row0 = blockIdx.x * 32;
  // ---- gate2 (verbatim)
  #pragma unroll
  for (int it = 0; it < 4; ++it) { int idx = tid + it*256; w2s[idx >> 3][idx & 7] = Wg2[idx]; }
  if (tid < 128) {
    const float invn = 1.f / 32768.f;
    float m = statg1[tid]*invn, vv = fmaf(-m, m, statg1[128 + tid]*invn);
    float a = rsqrtf(vv + 1e-5f) * ggm[tid];
    cA[tid] = a; cB[tid] = fmaf(-m, a, bng[tid]);
  }
  #pragma unroll
  for (int it = 0; it < 4; ++it) {
    int idx = tid + it*256; int r = idx >> 5, cq = idx & 31;
    *(float4*)&gs[r][cq*4] = *(const float4*)&g1[(long)(row0 + r)*128 + cq*4];
  }
  __syncthreads();
  {
    int r = tid >> 3, g = tid & 7;
    float acc = bg2[g];
    #pragma unroll 8
    for (int c2 = 0; c2 < 128; ++c2) {
      float act = fmaxf(0.f, fmaf(gs[r][c2], cA[c2], cB[c2]));
      acc = fmaf(act, w2s[c2][g], acc);
    }
    gt[r][g] = 1.f / (1.f + expf(-acc));
  }
  // ---- attention consts hoisted
  int rh = tid >> 7, t = tid & 127;
  int kk = t >> 3, g = t & 7;
  const float invnk = 1.f / 524288.f;
  float m0 = stath[g]*invnk, v0 = fmaf(-m0, m0, stath[8 + g]*invnk);
  float aw = rsqrtf(v0 + 1e-5f) * gw[g];
  float bw = fmaf(-m0, aw, bnw[g]);
  float w2r[8];
  #pragma unroll
  for (int g2 = 0; g2 < 8; ++g2) w2r[g2] = Ww2[g2*8 + g];
  float bw2g = bw2[g];
  __syncthreads();                 // gt ready; gs dead
  for (int itr = 0; itr < 16; ++itr) {
    int nl = itr*2 + rh;
    int n = row0 + nl;
    if (t < 16) smr[rh][t] = ref[n*16 + t];
    __syncthreads();
    int rr = smr[rh][kk];
    float h = kw[(long)rr*8 + g] - qw[(long)n*8 + g];
    sm1[rh][kk][g] = fmaxf(0.f, fmaf(h, aw, bw));
    __syncthreads();
    float acc = bw2g;
    #pragma unroll
    for (int g2 = 0; g2 < 8; ++g2) acc = fmaf(sm1[rh][kk][g2], w2r[g2], acc);
    float refined = acc * (1.f + gt[nl][g]);
    sm2[rh][kk][g] = refined;
    __syncthreads();
    float mx = -1e30f;
    #pragma unroll
    for (int k2 = 0; k2 < 16; ++k2) mx = fmaxf(mx, sm2[rh][k2][g]);
    float e = expf(refined - mx);
    sm1[rh][kk][g] = e;
    __syncthreads();
    float ssum = 0.f;
    #pragma unroll
    for (int k2 = 0; k2 < 16; ++k2) ssum += sm1[rh][k2][g];
    float mask = ((rr + 1) > 0) ? 1.f : (((rr + 1) == 0) ? 0.f : -1.f);
    float attn = e / ssum * mask;
    sm2[rh][kk][g] = attn;
    __syncthreads();
    float o = 0.f;
    #pragma unroll
    for (int k2 = 0; k2 < 16; ++k2) {
      float vv = bf2f(vb[(long)smr[rh][k2]*128 + t]);
      o = fmaf(vv, sm2[rh][k2][t >> 4], o);
    }
    out[(long)n*128 + t] = o;
    __syncthreads();               // fence before smr/sm reuse next iteration
  }
}

// ---------------------------------------------------------------------------
extern "C" void kernel_launch(void* const* d_in, const int* in_sizes, int n_in,
                              void* d_out, int out_size, void* d_ws, size_t ws_size,
                              hipStream_t stream)
{
  const float* feat  = (const float*)d_in[0];
  const float* coord = (const float*)d_in[1];
  const int*   ref   = (const int*)d_in[2];
  const float* Wq  = (const float*)d_in[4];
  const float* bq  = (const float*)d_in[5];
  const float* gq  = (const float*)d_in[6];
  const float* bnq = (const float*)d_in[7];
  const float* Wk  = (const float*)d_in[8];
  const float* bk  = (const float*)d_in[9];
  const float* gk  = (const float*)d_in[10];
  const float* bnk = (const float*)d_in[11];
  const float* Wv  = (const float*)d_in[12];
  const float* bv  = (const float*)d_in[13];
  const float* Sp  = (const float*)d_in[14];
  const float* Ww1 = (const float*)d_in[15];
  const float* bw1 = (const float*)d_in[16];
  const float* gw  = (const float*)d_in[17];
  const float* bnw = (const float*)d_in[18];
  const float* Ww2 = (const float*)d_in[19];
  const float* bw2 = (const float*)d_in[20];
  const float* Wg1 = (const float*)d_in[21];
  const float* bg1 = (const float*)d_in[22];
  const float* ggm = (const float*)d_in[23];
  const float* bng = (const float*)d_in[24];
  const float* Wg2 = (const float*)d_in[25];
  const float* bg2 = (const float*)d_in[26];
  float* out = (float*)d_out;

  float* W = (float*)d_ws;
  float* PW = W + OF_PW;
  short* WqT   = (short*)(W + OF_WQT);
  short* WkT   = (short*)(W + OF_WKT);
  short* WvT   = (short*)(W + OF_WVT);
  short* Wg1T  = (short*)(W + OF_WG1T);
  short* PTmIT = (short*)(W + OF_PTMIT);
  float* G1 = W + OF_G1;
  short* Vb = (short*)(W + OF_V);   // V stored bf16 (round 13)

  // 1: Cayley via per-column Neumann + weight bf16 transposes + stat zeroing
  cayley<<<81, 256, 0, stream>>>(Sp, Ww1, Wq, Wk, Wv, Wg1,
                                 WqT, WkT, WvT, Wg1T, PTmIT, PW, W + OF_STATQ);
  // 2: q/k GEMM -> stats/minmax; v GEMM -> bf16 store
  qkv_mfma<<<512, 256, 0, stream>>>(feat, WqT, WkT, WvT, bq, bk, bv, Vb,
                                    W + OF_STATQ, W + OF_STATK,
                                    (unsigned*)(W + OF_UMAXP), (unsigned*)(W + OF_UMAXN));
  // 2b: hoisted per-segment gate vector
  gprep<<<4, 128, 0, stream>>>(W + OF_STATQ, gq, bnq, bq,
                               (const unsigned*)(W + OF_UMAXP),
                               (const unsigned*)(W + OF_UMAXN),
                               Wg1, bg1, W + OF_GSG);
  // 3: recompute lin + BN + rotate + rope + project + g1(+stats)
  rqkw<<<512, 256, 0, stream>>>(feat, WqT, WkT, PTmIT, Wg1T, coord,
                                bq, bk,
                                W + OF_STATQ, W + OF_STATK,
                                gq, bnq, gk, bnk,
                                W + OF_GSG, PW, bw1,
                                W + OF_QW, W + OF_KW, G1, W + OF_STATG1);
  // 4: h statistics (global over all (n,k))
  hstat_k<<<1024, 256, 0, stream>>>(W + OF_KW, W + OF_QW, ref, W + OF_STATH);
  // 5: gate2 (in-LDS) + final attention + bf16 V gather, 32 rows/block
  attn2<<<1024, 256, 0, stream>>>(G1, W + OF_STATG1, ggm, bng, Wg2, bg2,
                                  W + OF_QW, W + OF_KW, W + OF_STATH,
                                  gw, bnw, Ww2, bw2, ref, Vb, out);
}

// Round 14
// 275.557 us; speedup vs baseline: 1.0742x; 1.0504x over previous
//
#include <hip/hip_runtime.h>
#include <math.h>

// Problem constants (fixed shapes)
#define N_PTS 32768
#define C_DIM 128
#define K_NB  16
#define G_DIM 8

// Workspace float offsets
#define OF_PW     0          // 128*8  P @ Ww1 (fp32)
#define OF_STATQ  1024       // 256 (sum, sumsq) of q_lin
#define OF_STATK  1280       // 256
#define OF_STATG1 1536       // 256
#define OF_STATH  1792       // 16
#define OF_UMAXP  1808       // 4*128 encoded max(q_lin raw) per seg
#define OF_UMAXN  2320       // 4*128 encoded max(-q_lin raw) per seg (zero region = 1024..2832)
#define OF_GSG    2832       // 4*128 precomputed gate-seg vector (gprep)
// bf16 [n][k] operands, 16384 shorts = 8192 floats each
#define OF_WQT    4096
#define OF_WKT    12288
#define OF_WVT    20480
#define OF_WG1T   28672
#define OF_PTMIT  36864
#define OF_QW     65536      // N*8
#define OF_KW     327680     // N*8
#define OF_GATE   589824     // N*8 (unused — gate lives in LDS)
#define OF_G1     1048576    // N*128
#define OF_V      5242880    // N*128 region; V stored as bf16 (N*128 shorts)

typedef short bf16x8 __attribute__((ext_vector_type(8)));
typedef float f32x4  __attribute__((ext_vector_type(4)));

#define LSTR 136   // bf16 LDS row stride (272 B) — cayley tiles

__device__ __forceinline__ unsigned f2bf(float f) {
  unsigned u = __float_as_uint(f);
  return (u + 0x7fffu + ((u >> 16) & 1u)) >> 16;
}
__device__ __forceinline__ float bf2f(short s) {
  return __uint_as_float(((unsigned)(unsigned short)s) << 16);
}
__device__ __forceinline__ unsigned fenc(float f) {
  unsigned b = __float_as_uint(f);
  return (b & 0x80000000u) ? ~b : (b | 0x80000000u);
}
__device__ __forceinline__ float fdec(unsigned u) {
  unsigned b = (u & 0x80000000u) ? (u & 0x7fffffffu) : ~u;
  return __uint_as_float(b);
}
__device__ __forceinline__ bf16x8 pack_bf8(float4 a, float4 b) {
  bf16x8 r;
  r[0] = (short)f2bf(a.x); r[1] = (short)f2bf(a.y);
  r[2] = (short)f2bf(a.z); r[3] = (short)f2bf(a.w);
  r[4] = (short)f2bf(b.x); r[5] = (short)f2bf(b.y);
  r[6] = (short)f2bf(b.z); r[7] = (short)f2bf(b.w);
  return r;
}

// async 16B global -> LDS (no VGPR round-trip, drained by __syncthreads)
__device__ __forceinline__ void g2l16(const void* g, void* l) {
  __builtin_amdgcn_global_load_lds(
      (const __attribute__((address_space(1))) void*)g,
      (__attribute__((address_space(3))) void*)l, 16, 0, 0);
}

// Async-stage a [128][128] bf16 tile (32 KB) into LINEAR LDS.
// Pre-swizzled global source (involution byte ^ ((row&7)<<4)) so the
// swizzled ds_reads in mfma1 are bank-balanced. Validated rounds 3-13.
__device__ __forceinline__ void stage_async(short* dst, const short* __restrict__ src, int tid) {
  int lane = tid & 63, wv = tid >> 6;
  #pragma unroll
  for (int it = 0; it < 8; ++it) {
    int chunk = it*256 + wv*64;            // wave-uniform 16B-chunk base
    int D = (chunk + lane)*16;             // this lane's linear LDS byte offset
    int gs = D ^ (((D >> 8) & 7) << 4);    // inverse (== forward) swizzle
    g2l16((const char*)src + gs, (char*)dst + chunk*16);
  }
}

// One 16x16x32 MFMA column-tile over swizzle-staged LDS B: returns af @ B
// for output col group; caller passes row = nt*16 + l15.
__device__ __forceinline__ f32x4 mfma1(const short* Bb, const bf16x8* a4, int row, int quad) {
  f32x4 ac = {0.f, 0.f, 0.f, 0.f};
  int sx = (row & 7) << 4;
  #pragma unroll
  for (int ks = 0; ks < 4; ++ks) {
    const char* p = (const char*)Bb + (((row*256) + ks*64 + quad*16) ^ sx);
    ac = __builtin_amdgcn_mfma_f32_16x16x32_bf16(a4[ks], *(const bf16x8*)p, ac, 0, 0, 0);
  }
  return ac;
}

// ---------------------------------------------------------------------------
// cayley: unchanged from round 8 (coalesced staging, validated).
__global__ __launch_bounds__(256) void cayley(const float* __restrict__ Sp,
    const float* __restrict__ Ww1,
    const float* __restrict__ Wq, const float* __restrict__ Wk,
    const float* __restrict__ Wv, const float* __restrict__ Wg1,
    short* __restrict__ WqT, short* __restrict__ WkT,
    short* __restrict__ WvT, short* __restrict__ Wg1T,
    short* __restrict__ PTmIT, float* __restrict__ PW,
    float* __restrict__ statz)
{
  __shared__ __align__(16) short Ssh[128*LSTR];
  __shared__ float x0[128], x1[128];
  int bx = blockIdx.x, tid = threadIdx.x;
  if (bx >= 64) {
    if (bx < 80) {
      int idx = bx - 64, widx = idx >> 2, qr = idx & 3;
      const float* src = (widx == 0) ? Wq : (widx == 1) ? Wk : (widx == 2) ? Wv : Wg1;
      short* dst = (widx == 0) ? WqT : (widx == 1) ? WkT : (widx == 2) ? WvT : Wg1T;
      const float4* s4 = (const float4*)src;
      short* T = Ssh;                    // [128][40] shorts: 80B rows, 16B-aligned
      #pragma unroll
      for (int it = 0; it < 4; ++it) {
        int q = it*256 + tid; int kloc = q >> 5, n4 = q & 31;
        float4 v = s4[(qr*32 + kloc)*32 + n4];
        T[(n4*4+0)*40 + kloc] = (short)f2bf(v.x);
        T[(n4*4+1)*40 + kloc] = (short)f2bf(v.y);
        T[(n4*4+2)*40 + kloc] = (short)f2bf(v.z);
        T[(n4*4+3)*40 + kloc] = (short)f2bf(v.w);
      }
      __syncthreads();
      #pragma unroll
      for (int it = 0; it < 2; ++it) {
        int i2 = it*256 + tid;           // 512 chunks of 8 shorts (128 rows x 4)
        int n = i2 >> 2, part = i2 & 3;
        uint4 val = *(const uint4*)&T[n*40 + part*8];
        *(uint4*)&dst[n*128 + qr*32 + part*8] = val;
      }
    } else {
      #pragma unroll
      for (int it = 0; it < 8; ++it) {
        int idx = it*256 + tid;
        if (idx < 1808) statz[idx] = 0.f;
      }
    }
    return;
  }
  int c0 = bx*2, c1 = c0 + 1;
  // stage antisymmetrized S: coalesced row reads; mirror for lower triangle
  {
    const float4* s4 = (const float4*)Sp;
    #pragma unroll
    for (int it = 0; it < 16; ++it) {
      int idx = it*256 + tid;            // 4096 float4 chunks, row-major
      int i = idx >> 5, j0 = (idx & 31) * 4;
      float4 v = s4[idx];
      #pragma unroll
      for (int u = 0; u < 4; ++u) {
        int j = j0 + u;
        float val = (&v.x)[u];
        if (j > i) {
          unsigned b = f2bf(val);
          Ssh[i*LSTR + j] = (short)b;                    // upper:  bf16(v)
          Ssh[j*LSTR + i] = (short)(b ^ 0x8000u);        // lower: -bf16(v) == bf16(-v)
        } else if (j == i) {
          Ssh[i*LSTR + j] = 0;                           // diagonal
        }
      }
    }
  }
  if (tid < 128) {
    x0[tid] = (tid == c0) ? 1.f : 0.f;
    x1[tid] = (tid == c1) ? 1.f : 0.f;
  }
  __syncthreads();
  int i = tid >> 1, h = tid & 1;
  const short* srow = &Ssh[i*LSTR + h*64];
  for (int t = 0; t < 16; ++t) {
    float a0 = 0.f, a1 = 0.f;
    #pragma unroll
    for (int jq = 0; jq < 16; ++jq) {
      short4 sv = *(const short4*)&srow[jq*4];
      #pragma unroll
      for (int u = 0; u < 4; ++u) {
        float s = bf2f((&sv.x)[u]);
        int j = h*64 + jq*4 + u;
        a0 = fmaf(s, x0[j], a0);
        a1 = fmaf(s, x1[j], a1);
      }
    }
    a0 += __shfl_xor(a0, 1);
    a1 += __shfl_xor(a1, 1);
    __syncthreads();
    if (h == 0) {
      x0[i] = a0 + ((i == c0) ? 1.f : 0.f);
      x1[i] = a1 + ((i == c1) ? 1.f : 0.f);
    }
    __syncthreads();
  }
  if (tid < 128) {
    PTmIT[c0*128 + tid] = (short)f2bf(2.f*x0[tid] - ((tid == c0) ? 2.f : 0.f));
  } else {
    int t = tid - 128;
    PTmIT[c1*128 + t] = (short)f2bf(2.f*x1[t] - ((t == c1) ? 2.f : 0.f));
  }
  if (tid < 16) {
    int cc = tid >> 3, g = tid & 7;
    const float* xv = cc ? x1 : x0;
    int c = cc ? c1 : c0;
    float acc = 0.f;
    #pragma unroll 8
    for (int j = 0; j < 128; ++j) acc = fmaf(xv[j], Ww1[j*8 + g], acc);
    PW[c*8 + g] = 2.f*acc - Ww1[c*8 + g];
  }
}

// ---------------------------------------------------------------------------
// qkv: unchanged from round 13 (V stored bf16).
__global__ __launch_bounds__(256, 2) void qkv_mfma(const float* __restrict__ feat,
    const short* __restrict__ WqT, const short* __restrict__ WkT, const short* __restrict__ WvT,
    const float* __restrict__ bq, const float* __restrict__ bk, const float* __restrict__ bv,
    short* __restrict__ Vb,
    float* __restrict__ statq, float* __restrict__ statk,
    unsigned* __restrict__ umaxp, unsigned* __restrict__ umaxn)
{
  __shared__ __align__(16) short Bb0[128*128];   // 32768 B
  __shared__ __align__(16) short Bb1[128*128];   // 32768 B
  __shared__ float ssum[2][128], ssq[2][128];
  __shared__ unsigned ump[128], umn[128];
  int tid = threadIdx.x, row0 = blockIdx.x * 64, seg = row0 >> 13;
  int lane = tid & 63, w = tid >> 6, l15 = lane & 15, quad = lane >> 4;
  stage_async(Bb0, WqT, tid);                  // async, in flight during setup
  if (tid < 128) {
    ssum[0][tid] = 0.f; ssum[1][tid] = 0.f;
    ssq[0][tid] = 0.f;  ssq[1][tid] = 0.f;
    ump[tid] = 0u; umn[tid] = 0u;
  }
  bf16x8 af[4];
  {
    long rbase = (long)(row0 + w*16 + l15) * 128;
    #pragma unroll
    for (int ks = 0; ks < 4; ++ks) {
      int c0 = ks*32 + quad*8;
      float4 v0 = *(const float4*)&feat[rbase + c0];
      float4 v1 = *(const float4*)&feat[rbase + c0 + 4];
      af[ks] = pack_bf8(v0, v1);
    }
  }
  __syncthreads();                       // S0: Bb0 staged, stats init
  stage_async(Bb1, WkT, tid);            // flies during GEMM-q
  // ---- q: GEMM + stats + raw minmax
  {
    #pragma unroll
    for (int nt = 0; nt < 8; ++nt) {
      f32x4 ac = mfma1(Bb0, af, nt*16 + l15, quad);
      int col = nt*16 + l15;
      float bb = bq[col];
      float s = 0.f, s2 = 0.f, mx = -1e30f, mn = 1e30f;
      #pragma unroll
      for (int r = 0; r < 4; ++r) {
        float raw = ac[r];
        float v = raw + bb;
        s += v; s2 = fmaf(v, v, s2);
        mx = fmaxf(mx, raw); mn = fminf(mn, raw);   // raw minmax (bias folded later)
      }
      s += __shfl_xor(s, 16); s += __shfl_xor(s, 32);
      s2 += __shfl_xor(s2, 16); s2 += __shfl_xor(s2, 32);
      mx = fmaxf(mx, __shfl_xor(mx, 16)); mx = fmaxf(mx, __shfl_xor(mx, 32));
      mn = fminf(mn, __shfl_xor(mn, 16)); mn = fminf(mn, __shfl_xor(mn, 32));
      if (lane < 16) {
        atomicAdd(&ssum[0][col], s); atomicAdd(&ssq[0][col], s2);
        atomicMax(&ump[col], fenc(mx)); atomicMax(&umn[col], fenc(-mn));
      }
    }
  }
  __syncthreads();                       // S1: Bb1 staged, Bb0 reads done
  stage_async(Bb0, WvT, tid);            // flies during GEMM-k
  // ---- k: GEMM + stats
  {
    #pragma unroll
    for (int nt = 0; nt < 8; ++nt) {
      f32x4 ac = mfma1(Bb1, af, nt*16 + l15, quad);
      int col = nt*16 + l15;
      float bb = bk[col];
      float s = 0.f, s2 = 0.f;
      #pragma unroll
      for (int r = 0; r < 4; ++r) {
        float v = ac[r] + bb;
        s += v; s2 = fmaf(v, v, s2);
      }
      s += __shfl_xor(s, 16); s += __shfl_xor(s, 32);
      s2 += __shfl_xor(s2, 16); s2 += __shfl_xor(s2, 32);
      if (lane < 16) { atomicAdd(&ssum[1][col], s); atomicAdd(&ssq[1][col], s2); }
    }
  }
  __syncthreads();                       // S2: Bb0(Wv) staged, Bb1 reads done
  // ---- v: GEMM + bf16 store
  {
    #pragma unroll
    for (int nt = 0; nt < 8; ++nt) {
      f32x4 ac = mfma1(Bb0, af, nt*16 + l15, quad);
      int col = nt*16 + l15;
      float bb = bv[col];
      #pragma unroll
      for (int r = 0; r < 4; ++r)
        Vb[(long)(row0 + w*16 + quad*4 + r)*128 + col] = (short)f2bf(ac[r] + bb);
    }
  }
  __syncthreads();                       // S3: LDS stats complete
  if (tid < 128) {
    atomicAdd(&statq[tid], ssum[0][tid]); atomicAdd(&statq[128 + tid], ssq[0][tid]);
    atomicAdd(&statk[tid], ssum[1][tid]); atomicAdd(&statk[128 + tid], ssq[1][tid]);
    atomicMax(&umaxp[seg*128 + tid], ump[tid]);
    atomicMax(&umaxn[seg*128 + tid], umn[tid]);
  }
}

// ---------------------------------------------------------------------------
// gprep: hoisted per-segment gate vector (unchanged, validated round 7).
__global__ __launch_bounds__(128) void gprep(
    const float* __restrict__ statq,
    const float* __restrict__ gq, const float* __restrict__ bnq,
    const float* __restrict__ bq,
    const unsigned* __restrict__ umaxp, const unsigned* __restrict__ umaxn,
    const float* __restrict__ Wg1, const float* __restrict__ bg1,
    float* __restrict__ gsgO)
{
  __shared__ float gml[128];
  int s = blockIdx.x, tid = threadIdx.x;   // 128 threads
  const float invn = 1.f / 32768.f;
  {
    float m = statq[tid]*invn, vv = fmaf(-m, m, statq[128 + tid]*invn);
    float a = rsqrtf(vv + 1e-5f) * gq[tid];
    float b = fmaf(-m, a, bnq[tid]);
    float cb2 = fmaf(a, bq[tid], b);
    float mx = fdec(umaxp[s*128 + tid]);
    float mn = -fdec(umaxn[s*128 + tid]);
    gml[tid] = fmaxf(0.f, fmaxf(fmaf(a, mx, cb2), fmaf(a, mn, cb2)));
  }
  __syncthreads();
  float acc = bg1[tid];
  #pragma unroll 8
  for (int j = 0; j < 128; ++j)
    acc = fmaf(gml[j], Wg1[(128 + j)*128 + tid], acc);
  gsgO[s*128 + tid] = acc;
}

// ---------------------------------------------------------------------------
// rqkw: round-9 validated form (unchanged).
__global__ __launch_bounds__(256, 2) void rqkw(
    const float* __restrict__ feat,
    const short* __restrict__ WqT, const short* __restrict__ WkT,
    const short* __restrict__ PTmIT, const short* __restrict__ Wg1T,
    const float* __restrict__ coord,
    const float* __restrict__ bq, const float* __restrict__ bk,
    const float* __restrict__ statq, const float* __restrict__ statk,
    const float* __restrict__ gq, const float* __restrict__ bnq,
    const float* __restrict__ gk, const float* __restrict__ bnk,
    const float* __restrict__ gsgG,
    const float* __restrict__ PW, const float* __restrict__ bw1,
    float* __restrict__ qw, float* __restrict__ kw,
    float* __restrict__ g1, float* __restrict__ statg1)
{
  __shared__ __align__(16) char arena[81920];
  short* Bb0  = (short*)arena;
  short* Bb1  = (short*)(arena + 32768);
  char*  bnS  = arena + 65536;               // 16384 B (64 rows x 256 B)
  float* xsq  = (float*)arena;
  float* xsk  = (float*)(arena + 33792);
  float* pws  = (float*)(arena + 67584);
  float* ssum4 = (float*)(arena + 71680);    // [4][128]
  float* ssq4  = (float*)(arena + 73728);    // [4][128]
  int tid = threadIdx.x, row0 = blockIdx.x * 64, seg = row0 >> 13;
  int lane = tid & 63, w = tid >> 6, l15 = lane & 15, quad = lane >> 4;
  stage_async(Bb0, WqT, tid);            // both weight tiles in flight
  stage_async(Bb1, WkT, tid);            // during all setup below
  bf16x8 af[4];
  {
    long rbase = (long)(row0 + w*16 + l15) * 128;
    #pragma unroll
    for (int ks = 0; ks < 4; ++ks) {
      int c0 = ks*32 + quad*8;
      float4 v0 = *(const float4*)&feat[rbase + c0];
      float4 v1 = *(const float4*)&feat[rbase + c0 + 4];
      af[ks] = pack_bf8(v0, v1);
    }
  }
  float caRq[8], cbRq[8], caRk[8], cbRk[8];
  {
    const float invn = 1.f / 32768.f;
    #pragma unroll
    for (int nt = 0; nt < 8; ++nt) {
      int col = nt*16 + l15;
      float m = statq[col]*invn, vv = fmaf(-m, m, statq[128 + col]*invn);
      float a = rsqrtf(vv + 1e-5f) * gq[col];
      float b = fmaf(-m, a, bnq[col]);
      caRq[nt] = a; cbRq[nt] = fmaf(a, bq[col], b);
      m = statk[col]*invn; vv = fmaf(-m, m, statk[128 + col]*invn);
      a = rsqrtf(vv + 1e-5f) * gk[col];
      b = fmaf(-m, a, bnk[col]);
      caRk[nt] = a; cbRk[nt] = fmaf(a, bk[col], b);
    }
  }
  float gsR[8];
  #pragma unroll
  for (int nt = 0; nt < 8; ++nt)
    gsR[nt] = gsgG[seg*128 + nt*16 + l15];
  __syncthreads();                       // S0: Bb0(Wq)+Bb1(Wk) staged
  float bnl_q[32], bnl_k[32];
  // ---- GEMM1q (ALL waves, Bb0) + BN -> bnS tile + bnl_q regs
  {
    #pragma unroll
    for (int nt = 0; nt < 8; ++nt) {
      f32x4 ac = mfma1(Bb0, af, nt*16 + l15, quad);
      int col = nt*16 + l15;
      float A = caRq[nt], B = cbRq[nt];
      #pragma unroll
      for (int r = 0; r < 4; ++r) {
        float v = fmaxf(0.f, fmaf(A, ac[r], B));
        bnl_q[nt*4 + r] = v;
        int row = w*16 + quad*4 + r;
        int ba = (row*256 + col*2) ^ ((row & 7) << 4);
        *(short*)(bnS + ba) = (short)f2bf(v);
      }
    }
  }
  __syncthreads();                       // S1: Bb0(Wq) reads done; bnS(q) done
  stage_async(Bb0, PTmIT, tid);          // hidden under GEMM1k
  // ---- GEMM1k (ALL waves, Bb1) -> bnl_k regs only
  {
    #pragma unroll
    for (int nt = 0; nt < 8; ++nt) {
      f32x4 ac = mfma1(Bb1, af, nt*16 + l15, quad);
      float A = caRk[nt], B = cbRk[nt];
      #pragma unroll
      for (int r = 0; r < 4; ++r)
        bnl_k[nt*4 + r] = fmaxf(0.f, fmaf(A, ac[r], B));
    }
  }
  __syncthreads();                       // S2: Bb0(PTmI) ready; Bb1 reads done
  stage_async(Bb1, Wg1T, tid);           // hidden under GEMM2q
  bf16x8 af2q[4];
  {
    int rowA = w*16 + l15, sx2 = (rowA & 7) << 4;
    #pragma unroll
    for (int ks = 0; ks < 4; ++ks)
      af2q[ks] = *(const bf16x8*)(bnS + ((rowA*256 + ks*64 + quad*16) ^ sx2));
  }
  // ---- GEMM2q: rotation for q (ALL waves, Bb0 = PTmI)
  f32x4 accv_q[8];
  #pragma unroll
  for (int nt = 0; nt < 8; ++nt)
    accv_q[nt] = mfma1(Bb0, af2q, nt*16 + l15, quad);
  __syncthreads();                       // S3: af2q reads done; Bb1(Wg1) ready
  // ---- rewrite bnS with bn(k)
  {
    #pragma unroll
    for (int nt = 0; nt < 8; ++nt) {
      int col = nt*16 + l15;
      #pragma unroll
      for (int r = 0; r < 4; ++r) {
        int row = w*16 + quad*4 + r;
        int ba = (row*256 + col*2) ^ ((row & 7) << 4);
        *(short*)(bnS + ba) = (short)f2bf(bnl_k[nt*4 + r]);
      }
    }
  }
  __syncthreads();                       // S4: bnS(k) complete
  bf16x8 af2k[4];
  {
    int rowA = w*16 + l15, sx2 = (rowA & 7) << 4;
    #pragma unroll
    for (int ks = 0; ks < 4; ++ks)
      af2k[ks] = *(const bf16x8*)(bnS + ((rowA*256 + ks*64 + quad*16) ^ sx2));
  }
  // ---- GEMM2k (Bb0 = PTmI) + GEMM3 (Bb1 = Wg1, af2q) with reg-held stats
  f32x4 accv_k[8];
  float sred[8], s2red[8];
  {
    #pragma unroll
    for (int nt = 0; nt < 8; ++nt) {
      accv_k[nt] = mfma1(Bb0, af2k, nt*16 + l15, quad);
      f32x4 ac = mfma1(Bb1, af2q, nt*16 + l15, quad);
      int col = nt*16 + l15;
      float gsv = gsR[nt];
      float s = 0.f, s2 = 0.f;
      #pragma unroll
      for (int r = 0; r < 4; ++r) {
        float v = ac[r] + gsv;
        g1[(long)(row0 + w*16 + quad*4 + r)*128 + col] = v;
        s += v; s2 = fmaf(v, v, s2);
      }
      s += __shfl_xor(s, 16); s += __shfl_xor(s, 32);
      s2 += __shfl_xor(s2, 16); s2 += __shfl_xor(s2, 32);
      sred[nt] = s; s2red[nt] = s2;
    }
  }
  __syncthreads();                       // S5: ALL LDS reads done -> arena free
  {
    #pragma unroll
    for (int nt = 0; nt < 8; ++nt) {
      int col = nt*16 + l15;
      #pragma unroll
      for (int r = 0; r < 4; ++r) {
        int row = w*16 + quad*4 + r;
        xsq[row*132 + col] = accv_q[nt][r] + bnl_q[nt*4 + r];
        xsk[row*132 + col] = accv_k[nt][r] + bnl_k[nt*4 + r];
      }
    }
  }
  #pragma unroll
  for (int it = 0; it < 4; ++it) { int idx = tid + it*256; pws[idx] = PW[idx]; }
  if (lane < 16) {
    #pragma unroll
    for (int nt = 0; nt < 8; ++nt) {
      ssum4[w*128 + nt*16 + l15] = sred[nt];
      ssq4[w*128 + nt*16 + l15] = s2red[nt];
    }
  }
  __syncthreads();                       // S6: xs + pws + scratch ready
  if (tid < 128) {
    float s = (ssum4[tid] + ssum4[128 + tid]) + (ssum4[256 + tid] + ssum4[384 + tid]);
    float s2 = (ssq4[tid] + ssq4[128 + tid]) + (ssq4[256 + tid] + ssq4[384 + tid]);
    atomicAdd(&statg1[tid], s);
    atomicAdd(&statg1[128 + tid], s2);
  }
  // rope: one sincos per (row, pair) applied to BOTH q and k (64 rows)
  #pragma unroll
  for (int it = 0; it < 16; ++it) {
    int idx = it*256 + tid;
    int r = idx >> 6, s = idx & 63;
    if (s < 63) {
      int a3 = s / 21, j = s - a3*21;
      int cr = a3*42 + j;
      float invf = exp2f((float)(2*j) * (-13.287712379549449f / 42.f));
      float ang = coord[(row0 + r)*3 + a3] * (2.0f * invf);
      float sn, co; sincosf(ang, &sn, &co);
      float fr = xsq[r*132 + cr], fi = xsq[r*132 + cr + 21];
      xsq[r*132 + cr]      = fr*co - fi*sn;
      xsq[r*132 + cr + 21] = fr*sn + fi*co;
      fr = xsk[r*132 + cr]; fi = xsk[r*132 + cr + 21];
      xsk[r*132 + cr]      = fr*co - fi*sn;
      xsk[r*132 + cr + 21] = fr*sn + fi*co;
    }
  }
  __syncthreads();                       // S7
  // projection: float4 LDS reads, 4 independent accumulators (64 rows x 2)
  #pragma unroll
  for (int it = 0; it < 4; ++it) {
    int idx = it*256 + tid;
    int mat = idx >> 9, r2 = (idx >> 3) & 63, g = idx & 7;
    const float* x2 = mat ? xsk : xsq;
    float a0 = 0.f, a1 = 0.f, a2 = 0.f, a3 = 0.f;
    #pragma unroll 8
    for (int i = 0; i < 128; i += 4) {
      float4 xv = *(const float4*)&x2[r2*132 + i];
      a0 = fmaf(xv.x, pws[(i+0)*8 + g], a0);
      a1 = fmaf(xv.y, pws[(i+1)*8 + g], a1);
      a2 = fmaf(xv.z, pws[(i+2)*8 + g], a2);
      a3 = fmaf(xv.w, pws[(i+3)*8 + g], a3);
    }
    float acc = (a0 + a1) + (a2 + a3) + (mat ? bw1[g] : 0.f);
    float* dst = mat ? kw : qw;
    dst[(long)(row0 + r2)*8 + g] = acc;
  }
}

// ---------------------------------------------------------------------------
// hstat_k: the hstat reduction (body verbatim; 1024 blocks).
__global__ __launch_bounds__(256) void hstat_k(
    const float* __restrict__ kw, const float* __restrict__ qw,
    const int* __restrict__ ref, float* __restrict__ stath)
{
  __shared__ float red[256];
  int tid = threadIdx.x;
  long base = (long)blockIdx.x * 4096;
  float s = 0.f, sq = 0.f;
  for (int it = 0; it < 16; ++it) {
    long idx = base + it*256 + tid;
    int n = (int)(idx >> 7); int kk = (int)((idx >> 3) & 15); int g = (int)(idx & 7);
    int r = ref[n*16 + kk];
    float h = kw[(long)r*8 + g] - qw[(long)n*8 + g];
    s += h; sq = fmaf(h, h, sq);
  }
  red[tid] = s; __syncthreads();
  for (int d = 128; d >= 8; d >>= 1) { if (tid < d) red[tid] += red[tid + d]; __syncthreads(); }
  if (tid < 8) atomicAdd(&stath[tid], red[tid]);
  __syncthreads();
  red[tid] = sq; __syncthreads();
  for (int d = 128; d >= 8; d >>= 1) { if (tid < d) red[tid] += red[tid + d]; __syncthreads(); }
  if (tid < 8) atomicAdd(&stath[8 + tid], red[tid]);
}

// ---------------------------------------------------------------------------
// attn2 ROUND 14: wave-per-row softmax — ZERO block barriers in the row loop
// (was 96/block). One wave owns a full row: lane l holds score elements
// (k=l>>3, g=l&7) and (k=8+(l>>3), g=l&7). Ww2 matvec via __shfl in the SAME
// g2 order as before (identical rounding); k-max via __shfl_xor (exact);
// k-sum via local+tree __shfl_xor (only numeric change, ~1 ulp of ssum).
// attn/smr bounce through PER-WAVE LDS scratch (same-wave write->read, no
// barrier). V gather: lane covers t=2l,2l+1 -> one uint load per (k,row),
// one attn weight serves both, float2 store. gate2 phase verbatim.
__global__ __launch_bounds__(256) void attn2(
    const float* __restrict__ g1, const float* __restrict__ statg1,
    const float* __restrict__ ggm, const float* __restrict__ bng,
    const float* __restrict__ Wg2, const float* __restrict__ bg2,
    const float* __restrict__ qw, const float* __restrict__ kw,
    const float* __restrict__ stath,
    const float* __restrict__ gw, const float* __restrict__ bnw,
    const float* __restrict__ Ww2, const float* __restrict__ bw2,
    const int* __restrict__ ref, const short* __restrict__ vb,
    float* __restrict__ out)
{
  __shared__ float gs[32][132];
  __shared__ float w2s[128][8];
  __shared__ float cA[128], cB[128];
  __shared__ float gt[32][8];
  __shared__ float ascr[4][128];   // per-wave attn scratch
  __shared__ int   rscr[4][16];    // per-wave ref scratch
  int tid = threadIdx.x;
  int row0 = blockIdx.x * 32;
  // ---- gate2 (verbatim)
  #pragma unroll
  for (int it = 0; it < 4; ++it) { int idx = tid + it*256; w2s[idx >> 3][idx & 7] = Wg2[idx]; }
  if (tid < 128) {
    const float invn = 1.f / 32768.f;
    float m = statg1[tid]*invn, vv = fmaf(-m, m, statg1[128 + tid]*invn);
    float a = rsqrtf(vv + 1e-5f) * ggm[tid];
    cA[tid] = a; cB[tid] = fmaf(-m, a, bng[tid]);
  }
  #pragma unroll
  for (int it = 0; it < 4; ++it) {
    int idx = tid + it*256; int r = idx >> 5, cq = idx & 31;
    *(float4*)&gs[r][cq*4] = *(const float4*)&g1[(long)(row0 + r)*128 + cq*4];
  }
  __syncthreads();
  {
    int r = tid >> 3, g = tid & 7;
    float acc = bg2[g];
    #pragma unroll 8
    for (int c2 = 0; c2 < 128; ++c2) {
      float act = fmaxf(0.f, fmaf(gs[r][c2], cA[c2], cB[c2]));
      acc = fmaf(act, w2s[c2][g], acc);
    }
    gt[r][g] = 1.f / (1.f + expf(-acc));
  }
  // ---- per-lane constants (wave-per-row layout)
  int w = tid >> 6, lane = tid & 63;
  int gL = lane & 7;              // g of both score elements
  int kL = lane >> 3;             // low k of score elements (kL, kL+8)
  const float invnk = 1.f / 524288.f;
  float m0 = stath[gL]*invnk, v0 = fmaf(-m0, m0, stath[8 + gL]*invnk);
  float aw = rsqrtf(v0 + 1e-5f) * gw[gL];
  float bw = fmaf(-m0, aw, bnw[gL]);
  float w2r[8];
  #pragma unroll
  for (int g2 = 0; g2 < 8; ++g2) w2r[g2] = Ww2[g2*8 + gL];
  float bw2g = bw2[gL];
  __syncthreads();                 // gt ready; gs/w2s/cA/cB dead
  // ---- row loop: one wave per row, no block barriers
  for (int it = 0; it < 8; ++it) {
    int nl = it*4 + w;
    int n = row0 + nl;
    int rmy = 0;
    if (lane < 16) { rmy = ref[n*16 + lane]; rscr[w][lane] = rmy; }
    int rr0 = __shfl(rmy, kL);
    int rr1 = __shfl(rmy, kL + 8);
    float qv = qw[(long)n*8 + gL];
    // h + BN + relu  (same formulas/order as before)
    float s0 = fmaxf(0.f, fmaf(kw[(long)rr0*8 + gL] - qv, aw, bw));
    float s1 = fmaxf(0.f, fmaf(kw[(long)rr1*8 + gL] - qv, aw, bw));
    // Ww2 matvec, g2 = 0..7 in original order (identical rounding)
    float a0 = bw2g, a1 = bw2g;
    int gbase = kL*8;
    #pragma unroll
    for (int g2 = 0; g2 < 8; ++g2) {
      a0 = fmaf(__shfl(s0, gbase + g2), w2r[g2], a0);
      a1 = fmaf(__shfl(s1, gbase + g2), w2r[g2], a1);
    }
    float gtv1 = 1.f + gt[nl][gL];
    float r0 = a0 * gtv1;
    float r1 = a1 * gtv1;
    // max over k (exact under any order)
    float mx = fmaxf(r0, r1);
    mx = fmaxf(mx, __shfl_xor(mx, 8));
    mx = fmaxf(mx, __shfl_xor(mx, 16));
    mx = fmaxf(mx, __shfl_xor(mx, 32));
    float e0 = expf(r0 - mx), e1 = expf(r1 - mx);
    float ss = e0 + e1;
    ss += __shfl_xor(ss, 8); ss += __shfl_xor(ss, 16); ss += __shfl_xor(ss, 32);
    float mask0 = ((rr0 + 1) > 0) ? 1.f : (((rr0 + 1) == 0) ? 0.f : -1.f);
    float mask1 = ((rr1 + 1) > 0) ? 1.f : (((rr1 + 1) == 0) ? 0.f : -1.f);
    ascr[w][lane]      = e0 / ss * mask0;   // attn[kL][gL]
    ascr[w][lane + 64] = e1 / ss * mask1;   // attn[kL+8][gL]
    // V accumulate: t = 2*lane, 2*lane+1; attn group index = t>>4 = kL
    float o0 = 0.f, o1 = 0.f;
    #pragma unroll
    for (int k2 = 0; k2 < 16; ++k2) {
      int rr = rscr[w][k2];
      unsigned vv = *(const unsigned*)&vb[(long)rr*128 + 2*lane];
      float a = ascr[w][k2*8 + kL];
      o0 = fmaf(bf2f((short)(vv & 0xffffu)), a, o0);
      o1 = fmaf(bf2f((short)(vv >> 16)), a, o1);
    }
    *(float2*)&out[(long)n*128 + 2*lane] = make_float2(o0, o1);
  }
}

// ---------------------------------------------------------------------------
extern "C" void kernel_launch(void* const* d_in, const int* in_sizes, int n_in,
                              void* d_out, int out_size, void* d_ws, size_t ws_size,
                              hipStream_t stream)
{
  const float* feat  = (const float*)d_in[0];
  const float* coord = (const float*)d_in[1];
  const int*   ref   = (const int*)d_in[2];
  const float* Wq  = (const float*)d_in[4];
  const float* bq  = (const float*)d_in[5];
  const float* gq  = (const float*)d_in[6];
  const float* bnq = (const float*)d_in[7];
  const float* Wk  = (const float*)d_in[8];
  const float* bk  = (const float*)d_in[9];
  const float* gk  = (const float*)d_in[10];
  const float* bnk = (const float*)d_in[11];
  const float* Wv  = (const float*)d_in[12];
  const float* bv  = (const float*)d_in[13];
  const float* Sp  = (const float*)d_in[14];
  const float* Ww1 = (const float*)d_in[15];
  const float* bw1 = (const float*)d_in[16];
  const float* gw  = (const float*)d_in[17];
  const float* bnw = (const float*)d_in[18];
  const float* Ww2 = (const float*)d_in[19];
  const float* bw2 = (const float*)d_in[20];
  const float* Wg1 = (const float*)d_in[21];
  const float* bg1 = (const float*)d_in[22];
  const float* ggm = (const float*)d_in[23];
  const float* bng = (const float*)d_in[24];
  const float* Wg2 = (const float*)d_in[25];
  const float* bg2 = (const float*)d_in[26];
  float* out = (float*)d_out;

  float* W = (float*)d_ws;
  float* PW = W + OF_PW;
  short* WqT   = (short*)(W + OF_WQT);
  short* WkT   = (short*)(W + OF_WKT);
  short* WvT   = (short*)(W + OF_WVT);
  short* Wg1T  = (short*)(W + OF_WG1T);
  short* PTmIT = (short*)(W + OF_PTMIT);
  float* G1 = W + OF_G1;
  short* Vb = (short*)(W + OF_V);   // V stored bf16

  // 1: Cayley via per-column Neumann + weight bf16 transposes + stat zeroing
  cayley<<<81, 256, 0, stream>>>(Sp, Ww1, Wq, Wk, Wv, Wg1,
                                 WqT, WkT, WvT, Wg1T, PTmIT, PW, W + OF_STATQ);
  // 2: q/k GEMM -> stats/minmax; v GEMM -> bf16 store
  qkv_mfma<<<512, 256, 0, stream>>>(feat, WqT, WkT, WvT, bq, bk, bv, Vb,
                                    W + OF_STATQ, W + OF_STATK,
                                    (unsigned*)(W + OF_UMAXP), (unsigned*)(W + OF_UMAXN));
  // 2b: hoisted per-segment gate vector
  gprep<<<4, 128, 0, stream>>>(W + OF_STATQ, gq, bnq, bq,
                               (const unsigned*)(W + OF_UMAXP),
                               (const unsigned*)(W + OF_UMAXN),
                               Wg1, bg1, W + OF_GSG);
  // 3: recompute lin + BN + rotate + rope + project + g1(+stats)
  rqkw<<<512, 256, 0, stream>>>(feat, WqT, WkT, PTmIT, Wg1T, coord,
                                bq, bk,
                                W + OF_STATQ, W + OF_STATK,
                                gq, bnq, gk, bnk,
                                W + OF_GSG, PW, bw1,
                                W + OF_QW, W + OF_KW, G1, W + OF_STATG1);
  // 4: h statistics (global over all (n,k))
  hstat_k<<<1024, 256, 0, stream>>>(W + OF_KW, W + OF_QW, ref, W + OF_STATH);
  // 5: gate2 (in-LDS) + wave-per-row attention + bf16 V gather
  attn2<<<1024, 256, 0, stream>>>(G1, W + OF_STATG1, ggm, bng, Wg2, bg2,
                                  W + OF_QW, W + OF_KW, W + OF_STATH,
                                  gw, bnw, Ww2, bw2, ref, Vb, out);
}